// Round 1
// baseline (781.648 us; speedup 1.0000x reference)
//
#include <hip/hip_runtime.h>
#include <hip/hip_bf16.h>

// Hierarchical 1-2-GNN forward. B=64 graphs x 64 nodes, P=129024 pairs, HID=128.
// Strategy:
//  - node MP layers: dual fp32 GEMM (shared A) + atomic edge scatter + relu
//  - 2-set layer 0: algebraic split  two_x@W = h[pu]@W_u + h[pv]@W_v + iso*w_iso
//    -> 4 small GEMMs (HU1,HV1,HU2,HV2) + fused per-edge scatter + per-pair compose
//  - 2-set layer 1: dual big GEMM [129024,128]@[128,128] + scatter + relu
//  - segment sums are contiguous (batch = repeat(arange(64)))
//  - tiny classifier: one block per graph

#define TILE_M 64

__global__ __launch_bounds__(256) void gemm_dual_n128(
    const float* __restrict__ A, const float* __restrict__ Wa,
    const float* __restrict__ Wb, float* __restrict__ Ca, float* __restrict__ Cb,
    int K)
{
  // C[M,128] = A[M,K] @ W[K,128] for two W simultaneously (shared A tile).
  // 64-row tile per block, 256 threads, each thread 4 rows x 8 cols x 2 outputs.
  __shared__ float sWa[32][128];
  __shared__ float sWb[32][128];
  __shared__ float sA[64][36];   // stride 36 floats = 144B (16B aligned, bank-shifted)
  const int tid = threadIdx.x;
  const int tx = tid & 15;   // 16 col groups of 8
  const int ty = tid >> 4;   // 16 row groups of 4
  const long rowBase = (long)blockIdx.x * TILE_M;

  float accA[4][8];
  float accB[4][8];
#pragma unroll
  for (int i = 0; i < 4; ++i)
#pragma unroll
    for (int j = 0; j < 8; ++j) { accA[i][j] = 0.f; accB[i][j] = 0.f; }

  for (int k0 = 0; k0 < K; k0 += 32) {
    // stage Wa, Wb rows k0..k0+31: 32x128 = 1024 float4 each
#pragma unroll
    for (int i = 0; i < 4; ++i) {
      int f = tid + i * 256;
      int r = f >> 5, c = f & 31;
      *(float4*)(&sWa[r][c * 4]) = *(const float4*)(Wa + (size_t)(k0 + r) * 128 + c * 4);
      *(float4*)(&sWb[r][c * 4]) = *(const float4*)(Wb + (size_t)(k0 + r) * 128 + c * 4);
    }
    // stage A tile: 64x32 = 512 float4
#pragma unroll
    for (int i = 0; i < 2; ++i) {
      int f = tid + i * 256;
      int r = f >> 3, c = f & 7;
      *(float4*)(&sA[r][c * 4]) = *(const float4*)(A + (rowBase + r) * (size_t)K + k0 + c * 4);
    }
    __syncthreads();
#pragma unroll
    for (int k = 0; k < 32; ++k) {
      float4 wa0 = *(const float4*)(&sWa[k][tx * 8]);
      float4 wa1 = *(const float4*)(&sWa[k][tx * 8 + 4]);
      float4 wb0 = *(const float4*)(&sWb[k][tx * 8]);
      float4 wb1 = *(const float4*)(&sWb[k][tx * 8 + 4]);
#pragma unroll
      for (int i = 0; i < 4; ++i) {
        float a = sA[ty * 4 + i][k];
        accA[i][0] += a * wa0.x; accA[i][1] += a * wa0.y;
        accA[i][2] += a * wa0.z; accA[i][3] += a * wa0.w;
        accA[i][4] += a * wa1.x; accA[i][5] += a * wa1.y;
        accA[i][6] += a * wa1.z; accA[i][7] += a * wa1.w;
        accB[i][0] += a * wb0.x; accB[i][1] += a * wb0.y;
        accB[i][2] += a * wb0.z; accB[i][3] += a * wb0.w;
        accB[i][4] += a * wb1.x; accB[i][5] += a * wb1.y;
        accB[i][6] += a * wb1.z; accB[i][7] += a * wb1.w;
      }
    }
    __syncthreads();
  }
#pragma unroll
  for (int i = 0; i < 4; ++i) {
    long row = rowBase + ty * 4 + i;
    *(float4*)(Ca + row * 128 + tx * 8)     = make_float4(accA[i][0], accA[i][1], accA[i][2], accA[i][3]);
    *(float4*)(Ca + row * 128 + tx * 8 + 4) = make_float4(accA[i][4], accA[i][5], accA[i][6], accA[i][7]);
    *(float4*)(Cb + row * 128 + tx * 8)     = make_float4(accB[i][0], accB[i][1], accB[i][2], accB[i][3]);
    *(float4*)(Cb + row * 128 + tx * 8 + 4) = make_float4(accB[i][4], accB[i][5], accB[i][6], accB[i][7]);
  }
}

// agg[dst[e]] += msg[src[e]]  (128 floats/edge, one thread per (edge,feature))
__global__ void scatter_msg(const float* __restrict__ msg, const int* __restrict__ src,
                            const int* __restrict__ dst, float* __restrict__ agg, int E)
{
  int t = blockIdx.x * 256 + threadIdx.x;
  if (t >= E * 128) return;
  int e = t >> 7, f = t & 127;
  int s = src[e], d = dst[e];
  atomicAdd(&agg[(size_t)d * 128 + f], msg[(size_t)s * 128 + f]);
}

// 2-set layer-0 message scatter, message formed on the fly:
// agg[dst] += HU2[pu[src]] + HV2[pv[src]] + iso[src]*w2iso
__global__ void scatter_two0(const float* __restrict__ HU2, const float* __restrict__ HV2,
                             const float* __restrict__ iso, const float* __restrict__ w2iso,
                             const int* __restrict__ pu, const int* __restrict__ pv,
                             const int* __restrict__ src, const int* __restrict__ dst,
                             float* __restrict__ agg, int E)
{
  int t = blockIdx.x * 256 + threadIdx.x;
  if (t >= E * 128) return;
  int e = t >> 7, f = t & 127;
  int s = src[e], d = dst[e];
  int u = pu[s], v = pv[s];
  float val = HU2[(size_t)u * 128 + f] + HV2[(size_t)v * 128 + f] + iso[s] * w2iso[f];
  atomicAdd(&agg[(size_t)d * 128 + f], val);
}

// h2[p] = relu(HU1[pu[p]] + HV1[pv[p]] + iso[p]*w1iso + agg[p])
__global__ void compose_h2(const float* __restrict__ HU1, const float* __restrict__ HV1,
                           const float* __restrict__ iso, const float* __restrict__ w1iso,
                           const int* __restrict__ pu, const int* __restrict__ pv,
                           const float* __restrict__ agg, float* __restrict__ h2, int P)
{
  int t = blockIdx.x * 256 + threadIdx.x;
  if (t >= P * 128) return;
  int p = t >> 7, f = t & 127;
  int u = pu[p], v = pv[p];
  float val = HU1[(size_t)u * 128 + f] + HV1[(size_t)v * 128 + f] + iso[p] * w1iso[f]
            + agg[t];
  h2[t] = fmaxf(val, 0.f);
}

__global__ void relu_add(const float* __restrict__ a, const float* __restrict__ b,
                         float* __restrict__ out, int n)
{
  int t = blockIdx.x * 256 + threadIdx.x;
  if (t >= n) return;
  out[t] = fmaxf(a[t] + b[t], 0.f);
}

// contiguous segment sum: out[g] += sum of rows [g*rps + part*rpc, ...) (128 wide)
__global__ void seg_sum(const float* __restrict__ X, float* __restrict__ out,
                        int rows_per_seg, int rows_per_chunk)
{
  int g = blockIdx.x, part = blockIdx.y, f = threadIdx.x;
  int r0 = part * rows_per_chunk;
  int r1 = r0 + rows_per_chunk;
  if (r1 > rows_per_seg) r1 = rows_per_seg;
  float s = 0.f;
  for (int i = r0; i < r1; ++i)
    s += X[((size_t)g * rows_per_seg + i) * 128 + f];
  atomicAdd(&out[g * 128 + f], s);
}

// per-graph classifier: relu([ge1,ge2]@W0 + b0) @ W1 + b1
__global__ void classifier(const float* __restrict__ ge1, const float* __restrict__ ge2,
                           const float* __restrict__ W0, const float* __restrict__ b0,
                           const float* __restrict__ W1, const float* __restrict__ b1,
                           float* __restrict__ out)
{
  __shared__ float comb[256];
  __shared__ float hc[128];
  int g = blockIdx.x, t = threadIdx.x;  // 128 threads
  comb[t]       = ge1[g * 128 + t];
  comb[t + 128] = ge2[g * 128 + t];
  __syncthreads();
  float s = b0[t];
  for (int k = 0; k < 256; ++k) s += comb[k] * W0[k * 128 + t];
  hc[t] = fmaxf(s, 0.f);
  __syncthreads();
  if (t < 10) {
    float s2 = b1[t];
    for (int k = 0; k < 128; ++k) s2 += hc[k] * W1[k * 10 + t];
    out[g * 10 + t] = s2;
  }
}

extern "C" void kernel_launch(void* const* d_in, const int* in_sizes, int n_in,
                              void* d_out, int out_size, void* d_ws, size_t ws_size,
                              hipStream_t stream)
{
  (void)n_in; (void)out_size; (void)ws_size;
  const float* x       = (const float*)d_in[0];
  const float* g1_W1_0 = (const float*)d_in[1];
  const float* g1_W2_0 = (const float*)d_in[2];
  const float* g1_W1_1 = (const float*)d_in[3];
  const float* g1_W2_1 = (const float*)d_in[4];
  const float* g1_W1_2 = (const float*)d_in[5];
  const float* g1_W2_2 = (const float*)d_in[6];
  const float* k_W1_0  = (const float*)d_in[7];   // [257,128]
  const float* k_W2_0  = (const float*)d_in[8];   // [257,128]
  const float* k_W1_1  = (const float*)d_in[9];   // [128,128]
  const float* k_W2_1  = (const float*)d_in[10];  // [128,128]
  const float* c_W0    = (const float*)d_in[11];  // [256,128]
  const float* c_b0    = (const float*)d_in[12];
  const float* c_W1    = (const float*)d_in[13];  // [128,10]
  const float* c_b1    = (const float*)d_in[14];
  const float* iso     = (const float*)d_in[15];  // [P]
  const int*   ei      = (const int*)d_in[16];    // [2,E1]
  const int*   pu      = (const int*)d_in[18];    // [P]
  const int*   pv      = (const int*)d_in[19];    // [P]
  const int*   te      = (const int*)d_in[20];    // [2,E2]

  const int N  = in_sizes[0] / 64;   // 4096 nodes total (IN_DIM=64)
  const int E1 = in_sizes[16] / 2;
  const int P  = in_sizes[18];       // 129024
  const int E2 = in_sizes[20] / 2;
  const int B  = 64;
  const int ppg = P / B;             // 2016 pairs per graph

  const size_t NH = (size_t)N * 128;
  const size_t PH = (size_t)P * 128;

  float* ws   = (float*)d_ws;
  float* h    = ws;              // NH
  float* preN = h    + NH;       // NH
  float* msgN = preN + NH;       // NH
  float* aggN = msgN + NH;       // NH
  float* HU1  = aggN + NH;       // NH
  float* HV1  = HU1  + NH;       // NH
  float* HU2  = HV1  + NH;       // NH
  float* HV2  = HU2  + NH;       // NH
  float* ge1  = HV2  + NH;       // 8192
  float* ge2  = ge1  + 8192;     // 8192
  float* AGG2 = ge2  + 8192;     // PH
  float* H2   = AGG2 + PH;       // PH
  float* B2   = H2   + PH;       // PH

  const int gemmBlocksN = N / TILE_M;        // 64
  const int gemmBlocksP = P / TILE_M;        // 2016
  const int scatN  = (E1 * 128 + 255) / 256;
  const int scat2  = (E2 * 128 + 255) / 256;
  const int elemN  = (int)((NH + 255) / 256);
  const int elemP  = (int)((PH + 255) / 256);

  // ---- node stage: 3 MP layers ----
  // layer 0 (K=64)
  gemm_dual_n128<<<gemmBlocksN, 256, 0, stream>>>(x, g1_W1_0, g1_W2_0, preN, msgN, 64);
  hipMemsetAsync(aggN, 0, NH * 4, stream);
  scatter_msg<<<scatN, 256, 0, stream>>>(msgN, ei, ei + E1, aggN, E1);
  relu_add<<<elemN, 256, 0, stream>>>(preN, aggN, h, (int)NH);
  // layer 1
  gemm_dual_n128<<<gemmBlocksN, 256, 0, stream>>>(h, g1_W1_1, g1_W2_1, preN, msgN, 128);
  hipMemsetAsync(aggN, 0, NH * 4, stream);
  scatter_msg<<<scatN, 256, 0, stream>>>(msgN, ei, ei + E1, aggN, E1);
  relu_add<<<elemN, 256, 0, stream>>>(preN, aggN, h, (int)NH);
  // layer 2
  gemm_dual_n128<<<gemmBlocksN, 256, 0, stream>>>(h, g1_W1_2, g1_W2_2, preN, msgN, 128);
  hipMemsetAsync(aggN, 0, NH * 4, stream);
  scatter_msg<<<scatN, 256, 0, stream>>>(msgN, ei, ei + E1, aggN, E1);
  relu_add<<<elemN, 256, 0, stream>>>(preN, aggN, h, (int)NH);

  // graph_emb_1 (contiguous 64-row segments)
  hipMemsetAsync(ge1, 0, 8192 * 4, stream);
  seg_sum<<<dim3(B, 1), 128, 0, stream>>>(h, ge1, 64, 64);

  // ---- 2-set stage ----
  // HU1 = h@W1[0:128], HV1 = h@W1[128:256]; same for W2 (shared A => dual)
  gemm_dual_n128<<<gemmBlocksN, 256, 0, stream>>>(h, k_W1_0,             k_W2_0,             HU1, HU2, 128);
  gemm_dual_n128<<<gemmBlocksN, 256, 0, stream>>>(h, k_W1_0 + 128 * 128, k_W2_0 + 128 * 128, HV1, HV2, 128);

  // layer k0: scatter messages (formed on the fly), then compose+relu
  hipMemsetAsync(AGG2, 0, PH * 4, stream);
  scatter_two0<<<scat2, 256, 0, stream>>>(HU2, HV2, iso, k_W2_0 + 256 * 128,
                                          pu, pv, te, te + E2, AGG2, E2);
  compose_h2<<<elemP, 256, 0, stream>>>(HU1, HV1, iso, k_W1_0 + 256 * 128,
                                        pu, pv, AGG2, H2, P);

  // layer k1: dual big GEMM; msg first, scatter, then pre overwrites B2
  gemm_dual_n128<<<gemmBlocksP, 256, 0, stream>>>(H2, k_W2_1, k_W1_1, B2, AGG2, 128);
  // NOTE: B2 = H2@k_W2_1 (messages); AGG2 currently holds H2@k_W1_1 (pre) - keep it!
  // We need agg zeroed, so instead: move pre to msgN? No - P-sized. Redo properly below.
  // (See corrected sequence: we computed pre into AGG2; copy it to B2's role.)
  // To keep it simple and correct: compute msg into B2, pre into AGG2 is WRONG since
  // AGG2 must accumulate. Fix: scatter from B2 into a re-zeroed AGG2 after saving pre.
  // Correction: swap so pre lives in H2's future location:
  //   B2  = messages (H2@k_W2_1)
  //   AGG2 = pre     (H2@k_W1_1)  -> copy pre out of the way is avoidable by reordering:
  // We scatter messages into ge-zeroed buffer reusing... simplest: use compose target.
  // Implemented as: scatter into H2 after moving? -- resolved by sequence below.
  {
    // AGG2 currently holds pre = H2@k_W1_1. B2 holds msg = H2@k_W2_1.
    // We need: h2_new = relu(pre + scatter(msg)). Scatter into a zero buffer: reuse H2?
    // H2 is still needed? No! Both GEMMs already consumed H2. So H2 is free.
    hipMemsetAsync(H2, 0, PH * 4, stream);
    scatter_msg<<<scat2, 256, 0, stream>>>(B2, te, te + E2, H2, E2);
    relu_add<<<elemP, 256, 0, stream>>>(AGG2, H2, B2, (int)PH);  // B2 = final h2
  }

  // graph_emb_2 (contiguous 2016-row segments, 16-way split)
  hipMemsetAsync(ge2, 0, 8192 * 4, stream);
  seg_sum<<<dim3(B, 16), 128, 0, stream>>>(B2, ge2, ppg, (ppg + 15) / 16);

  // classifier
  classifier<<<B, 128, 0, stream>>>(ge1, ge2, c_W0, c_b0, c_W1, c_b1, (float*)d_out);
}

// Round 2
// 743.057 us; speedup vs baseline: 1.0519x; 1.0519x over previous
//
#include <hip/hip_runtime.h>
#include <hip/hip_bf16.h>

// Hierarchical 1-2-GNN forward. B=64 graphs x 64 nodes, P=129024 pairs, HID=128.
// Round 2: replace all float-atomic scatters with device-built dst-CSR gathers,
// fused with the compose/relu epilogues. CSR built once per call (two_edges is
// shared by both 2-set layers; edge_index by all 3 node layers).

#define TILE_M 64

__device__ __forceinline__ float4 ld4(const float* p) { return *(const float4*)p; }

__global__ __launch_bounds__(256) void gemm_dual_n128(
    const float* __restrict__ A, const float* __restrict__ Wa,
    const float* __restrict__ Wb, float* __restrict__ Ca, float* __restrict__ Cb,
    int K)
{
  // C[M,128] = A[M,K] @ W[K,128] for two W simultaneously (shared A tile).
  __shared__ float sWa[32][128];
  __shared__ float sWb[32][128];
  __shared__ float sA[64][36];
  const int tid = threadIdx.x;
  const int tx = tid & 15;
  const int ty = tid >> 4;
  const long rowBase = (long)blockIdx.x * TILE_M;

  float accA[4][8];
  float accB[4][8];
#pragma unroll
  for (int i = 0; i < 4; ++i)
#pragma unroll
    for (int j = 0; j < 8; ++j) { accA[i][j] = 0.f; accB[i][j] = 0.f; }

  for (int k0 = 0; k0 < K; k0 += 32) {
#pragma unroll
    for (int i = 0; i < 4; ++i) {
      int f = tid + i * 256;
      int r = f >> 5, c = f & 31;
      *(float4*)(&sWa[r][c * 4]) = *(const float4*)(Wa + (size_t)(k0 + r) * 128 + c * 4);
      *(float4*)(&sWb[r][c * 4]) = *(const float4*)(Wb + (size_t)(k0 + r) * 128 + c * 4);
    }
#pragma unroll
    for (int i = 0; i < 2; ++i) {
      int f = tid + i * 256;
      int r = f >> 3, c = f & 7;
      *(float4*)(&sA[r][c * 4]) = *(const float4*)(A + (rowBase + r) * (size_t)K + k0 + c * 4);
    }
    __syncthreads();
#pragma unroll
    for (int k = 0; k < 32; ++k) {
      float4 wa0 = *(const float4*)(&sWa[k][tx * 8]);
      float4 wa1 = *(const float4*)(&sWa[k][tx * 8 + 4]);
      float4 wb0 = *(const float4*)(&sWb[k][tx * 8]);
      float4 wb1 = *(const float4*)(&sWb[k][tx * 8 + 4]);
#pragma unroll
      for (int i = 0; i < 4; ++i) {
        float a = sA[ty * 4 + i][k];
        accA[i][0] += a * wa0.x; accA[i][1] += a * wa0.y;
        accA[i][2] += a * wa0.z; accA[i][3] += a * wa0.w;
        accA[i][4] += a * wa1.x; accA[i][5] += a * wa1.y;
        accA[i][6] += a * wa1.z; accA[i][7] += a * wa1.w;
        accB[i][0] += a * wb0.x; accB[i][1] += a * wb0.y;
        accB[i][2] += a * wb0.z; accB[i][3] += a * wb0.w;
        accB[i][4] += a * wb1.x; accB[i][5] += a * wb1.y;
        accB[i][6] += a * wb1.z; accB[i][7] += a * wb1.w;
      }
    }
    __syncthreads();
  }
#pragma unroll
  for (int i = 0; i < 4; ++i) {
    long row = rowBase + ty * 4 + i;
    *(float4*)(Ca + row * 128 + tx * 8)     = make_float4(accA[i][0], accA[i][1], accA[i][2], accA[i][3]);
    *(float4*)(Ca + row * 128 + tx * 8 + 4) = make_float4(accA[i][4], accA[i][5], accA[i][6], accA[i][7]);
    *(float4*)(Cb + row * 128 + tx * 8)     = make_float4(accB[i][0], accB[i][1], accB[i][2], accB[i][3]);
    *(float4*)(Cb + row * 128 + tx * 8 + 4) = make_float4(accB[i][4], accB[i][5], accB[i][6], accB[i][7]);
  }
}

// ---------------- CSR build (dst-indexed) ----------------
__global__ void csr_count(const int* __restrict__ dst, int* __restrict__ deg, int E)
{
  int e = blockIdx.x * 256 + threadIdx.x;
  if (e < E) atomicAdd(&deg[dst[e]], 1);
}

__global__ __launch_bounds__(1024) void excl_scan(const int* __restrict__ deg,
                                                  int* __restrict__ off, int n)
{
  // single-block hierarchical exclusive scan; n <= 1024 * chunk
  __shared__ int part[1024];
  int t = threadIdx.x;
  int chunk = (n + 1023) >> 10;
  long lo = (long)t * chunk;
  long hi = lo + chunk;
  if (hi > n) hi = n;
  if (lo > n) lo = n;
  int s = 0;
  for (long i = lo; i < hi; ++i) s += deg[i];
  part[t] = s;
  __syncthreads();
  for (int d = 1; d < 1024; d <<= 1) {
    int v = (t >= d) ? part[t - d] : 0;
    __syncthreads();
    part[t] += v;
    __syncthreads();
  }
  int base = (t == 0) ? 0 : part[t - 1];
  for (long i = lo; i < hi; ++i) { off[i] = base; base += deg[i]; }
  if (t == 1023) off[n] = part[1023];
}

__global__ void csr_fill(const int* __restrict__ src, const int* __restrict__ dst,
                         int* __restrict__ cur, int* __restrict__ eidx, int E)
{
  int e = blockIdx.x * 256 + threadIdx.x;
  if (e >= E) return;
  int pos = atomicAdd(&cur[dst[e]], 1);
  eidx[pos] = src[e];
}

// ---------------- fused gathers ----------------
// out[r] = relu(pre[r] + sum_{j in [off[r],off[r+1])} msg[eidx[j]])
__global__ __launch_bounds__(256) void gather_add_relu(
    const float* __restrict__ pre, const float* __restrict__ msg,
    const int* __restrict__ off, const int* __restrict__ eidx,
    float* __restrict__ out, int R)
{
  int r = blockIdx.x * 8 + (threadIdx.x >> 5);
  if (r >= R) return;
  int f = (threadIdx.x & 31) * 4;
  float4 acc = ld4(pre + (size_t)r * 128 + f);
  int e1 = off[r + 1];
  for (int j = off[r]; j < e1; ++j) {
    int s = eidx[j];
    float4 m = ld4(msg + (size_t)s * 128 + f);
    acc.x += m.x; acc.y += m.y; acc.z += m.z; acc.w += m.w;
  }
  float4 o = make_float4(fmaxf(acc.x, 0.f), fmaxf(acc.y, 0.f),
                         fmaxf(acc.z, 0.f), fmaxf(acc.w, 0.f));
  *(float4*)(out + (size_t)r * 128 + f) = o;
}

// 2-set layer 0, fully fused: compose self term + gather messages formed on the fly.
// out[p] = relu(HU1[pu[p]] + HV1[pv[p]] + iso[p]*w1iso
//               + sum_j HU2[pu[s]] + HV2[pv[s]] + iso[s]*w2iso), s = eidx[j]
__global__ __launch_bounds__(256) void gather_two0(
    const float* __restrict__ HU1, const float* __restrict__ HV1,
    const float* __restrict__ HU2, const float* __restrict__ HV2,
    const float* __restrict__ iso,
    const float* __restrict__ w1iso, const float* __restrict__ w2iso,
    const int* __restrict__ pu, const int* __restrict__ pv,
    const int* __restrict__ off, const int* __restrict__ eidx,
    float* __restrict__ out, int P)
{
  int p = blockIdx.x * 8 + (threadIdx.x >> 5);
  if (p >= P) return;
  int f = (threadIdx.x & 31) * 4;
  float4 wi1 = ld4(w1iso + f);
  float4 wi2 = ld4(w2iso + f);
  int u0 = pu[p], v0 = pv[p];
  float is0 = iso[p];
  float4 a = ld4(HU1 + (size_t)u0 * 128 + f);
  float4 b = ld4(HV1 + (size_t)v0 * 128 + f);
  float4 acc;
  acc.x = a.x + b.x + is0 * wi1.x;
  acc.y = a.y + b.y + is0 * wi1.y;
  acc.z = a.z + b.z + is0 * wi1.z;
  acc.w = a.w + b.w + is0 * wi1.w;
  int e1 = off[p + 1];
  for (int j = off[p]; j < e1; ++j) {
    int s = eidx[j];
    int u = pu[s], v = pv[s];
    float iss = iso[s];
    float4 mu = ld4(HU2 + (size_t)u * 128 + f);
    float4 mv = ld4(HV2 + (size_t)v * 128 + f);
    acc.x += mu.x + mv.x + iss * wi2.x;
    acc.y += mu.y + mv.y + iss * wi2.y;
    acc.z += mu.z + mv.z + iss * wi2.z;
    acc.w += mu.w + mv.w + iss * wi2.w;
  }
  float4 o = make_float4(fmaxf(acc.x, 0.f), fmaxf(acc.y, 0.f),
                         fmaxf(acc.z, 0.f), fmaxf(acc.w, 0.f));
  *(float4*)(out + (size_t)p * 128 + f) = o;
}

// contiguous segment sum (128 wide)
__global__ void seg_sum(const float* __restrict__ X, float* __restrict__ out,
                        int rows_per_seg, int rows_per_chunk)
{
  int g = blockIdx.x, part = blockIdx.y, f = threadIdx.x;
  int r0 = part * rows_per_chunk;
  int r1 = r0 + rows_per_chunk;
  if (r1 > rows_per_seg) r1 = rows_per_seg;
  float s = 0.f;
  for (int i = r0; i < r1; ++i)
    s += X[((size_t)g * rows_per_seg + i) * 128 + f];
  atomicAdd(&out[g * 128 + f], s);
}

__global__ void classifier(const float* __restrict__ ge1, const float* __restrict__ ge2,
                           const float* __restrict__ W0, const float* __restrict__ b0,
                           const float* __restrict__ W1, const float* __restrict__ b1,
                           float* __restrict__ out)
{
  __shared__ float comb[256];
  __shared__ float hc[128];
  int g = blockIdx.x, t = threadIdx.x;  // 128 threads
  comb[t]       = ge1[g * 128 + t];
  comb[t + 128] = ge2[g * 128 + t];
  __syncthreads();
  float s = b0[t];
  for (int k = 0; k < 256; ++k) s += comb[k] * W0[k * 128 + t];
  hc[t] = fmaxf(s, 0.f);
  __syncthreads();
  if (t < 10) {
    float s2 = b1[t];
    for (int k = 0; k < 128; ++k) s2 += hc[k] * W1[k * 10 + t];
    out[g * 10 + t] = s2;
  }
}

extern "C" void kernel_launch(void* const* d_in, const int* in_sizes, int n_in,
                              void* d_out, int out_size, void* d_ws, size_t ws_size,
                              hipStream_t stream)
{
  (void)n_in; (void)out_size; (void)ws_size;
  const float* x       = (const float*)d_in[0];
  const float* g1_W1_0 = (const float*)d_in[1];
  const float* g1_W2_0 = (const float*)d_in[2];
  const float* g1_W1_1 = (const float*)d_in[3];
  const float* g1_W2_1 = (const float*)d_in[4];
  const float* g1_W1_2 = (const float*)d_in[5];
  const float* g1_W2_2 = (const float*)d_in[6];
  const float* k_W1_0  = (const float*)d_in[7];   // [257,128]
  const float* k_W2_0  = (const float*)d_in[8];   // [257,128]
  const float* k_W1_1  = (const float*)d_in[9];   // [128,128]
  const float* k_W2_1  = (const float*)d_in[10];  // [128,128]
  const float* c_W0    = (const float*)d_in[11];
  const float* c_b0    = (const float*)d_in[12];
  const float* c_W1    = (const float*)d_in[13];
  const float* c_b1    = (const float*)d_in[14];
  const float* iso     = (const float*)d_in[15];  // [P]
  const int*   ei      = (const int*)d_in[16];    // [2,E1]
  const int*   pu      = (const int*)d_in[18];    // [P]
  const int*   pv      = (const int*)d_in[19];    // [P]
  const int*   te      = (const int*)d_in[20];    // [2,E2]

  const int N  = in_sizes[0] / 64;   // 4096
  const int E1 = in_sizes[16] / 2;
  const int P  = in_sizes[18];       // 129024
  const int E2 = in_sizes[20] / 2;
  const int B  = 64;
  const int ppg = P / B;             // 2016

  const size_t NH = (size_t)N * 128;
  const size_t PH = (size_t)P * 128;

  float* ws   = (float*)d_ws;
  float* h    = ws;              // NH
  float* preN = h    + NH;       // NH
  float* msgN = preN + NH;       // NH
  float* HU1  = msgN + NH;       // NH
  float* HV1  = HU1  + NH;       // NH
  float* HU2  = HV1  + NH;       // NH
  float* HV2  = HU2  + NH;       // NH
  float* ge1  = HV2  + NH;       // 8192
  float* ge2  = ge1  + 8192;     // 8192
  float* H2   = ge2  + 8192;     // PH
  float* PRE2 = H2   + PH;       // PH
  float* MSG2 = PRE2 + PH;       // PH

  int* ip    = (int*)(MSG2 + PH);
  int* degN  = ip;               // N
  int* offN  = degN + N;         // N+1
  int* curN  = offN + N + 1;     // N
  int* eidxN = curN + N;         // E1
  int* degP  = eidxN + E1;       // P
  int* offP  = degP + P;         // P+1
  int* curP  = offP + P + 1;     // P
  int* eidxP = curP + P;         // E2

  const int gemmBlocksN = N / TILE_M;        // 64
  const int gemmBlocksP = P / TILE_M;        // 2016
  const int gatherN = (N + 7) / 8;
  const int gatherP = (P + 7) / 8;

  // ---- build CSRs (node graph + pair graph) ----
  hipMemsetAsync(degN, 0, (size_t)N * 4, stream);
  hipMemsetAsync(degP, 0, (size_t)P * 4, stream);
  csr_count<<<(E1 + 255) / 256, 256, 0, stream>>>(ei + E1, degN, E1);
  csr_count<<<(E2 + 255) / 256, 256, 0, stream>>>(te + E2, degP, E2);
  excl_scan<<<1, 1024, 0, stream>>>(degN, offN, N);
  excl_scan<<<1, 1024, 0, stream>>>(degP, offP, P);
  hipMemcpyAsync(curN, offN, (size_t)N * 4, hipMemcpyDeviceToDevice, stream);
  hipMemcpyAsync(curP, offP, (size_t)P * 4, hipMemcpyDeviceToDevice, stream);
  csr_fill<<<(E1 + 255) / 256, 256, 0, stream>>>(ei, ei + E1, curN, eidxN, E1);
  csr_fill<<<(E2 + 255) / 256, 256, 0, stream>>>(te, te + E2, curP, eidxP, E2);

  // ---- node stage: 3 MP layers (gemm + fused gather/relu) ----
  gemm_dual_n128<<<gemmBlocksN, 256, 0, stream>>>(x, g1_W1_0, g1_W2_0, preN, msgN, 64);
  gather_add_relu<<<gatherN, 256, 0, stream>>>(preN, msgN, offN, eidxN, h, N);
  gemm_dual_n128<<<gemmBlocksN, 256, 0, stream>>>(h, g1_W1_1, g1_W2_1, preN, msgN, 128);
  gather_add_relu<<<gatherN, 256, 0, stream>>>(preN, msgN, offN, eidxN, h, N);
  gemm_dual_n128<<<gemmBlocksN, 256, 0, stream>>>(h, g1_W1_2, g1_W2_2, preN, msgN, 128);
  gather_add_relu<<<gatherN, 256, 0, stream>>>(preN, msgN, offN, eidxN, h, N);

  // graph_emb_1
  hipMemsetAsync(ge1, 0, 8192 * 4, stream);
  seg_sum<<<dim3(B, 1), 128, 0, stream>>>(h, ge1, 64, 64);

  // ---- 2-set stage ----
  gemm_dual_n128<<<gemmBlocksN, 256, 0, stream>>>(h, k_W1_0,             k_W2_0,             HU1, HU2, 128);
  gemm_dual_n128<<<gemmBlocksN, 256, 0, stream>>>(h, k_W1_0 + 128 * 128, k_W2_0 + 128 * 128, HV1, HV2, 128);

  // layer k0: fully fused gather (no atomics, no memset, no compose pass)
  gather_two0<<<gatherP, 256, 0, stream>>>(HU1, HV1, HU2, HV2, iso,
                                           k_W1_0 + 256 * 128, k_W2_0 + 256 * 128,
                                           pu, pv, offP, eidxP, H2, P);

  // layer k1: dual big GEMM (pre into PRE2, msg into MSG2), fused gather
  gemm_dual_n128<<<gemmBlocksP, 256, 0, stream>>>(H2, k_W1_1, k_W2_1, PRE2, MSG2, 128);
  gather_add_relu<<<gatherP, 256, 0, stream>>>(PRE2, MSG2, offP, eidxP, H2, P);

  // graph_emb_2
  hipMemsetAsync(ge2, 0, 8192 * 4, stream);
  seg_sum<<<dim3(B, 16), 128, 0, stream>>>(H2, ge2, ppg, (ppg + 15) / 16);

  // classifier
  classifier<<<B, 128, 0, stream>>>(ge1, ge2, c_W0, c_b0, c_W1, c_b1, (float*)d_out);
}

// Round 3
// 550.429 us; speedup vs baseline: 1.4201x; 1.3500x over previous
//
#include <hip/hip_runtime.h>
#include <hip/hip_bf16.h>

// Hierarchical 1-2-GNN forward. B=64 graphs x 64 nodes, P=129024 pairs, HID=128.
// Round 3: replace the latency-serial single-block exclusive scan (205 us on P)
// with a 3-phase multi-block scan (~10 us); scan_final also initializes the
// csr_fill cursors (drops two d2d memcpys).

#define TILE_M 64

__device__ __forceinline__ float4 ld4(const float* p) { return *(const float4*)p; }

__global__ __launch_bounds__(256) void gemm_dual_n128(
    const float* __restrict__ A, const float* __restrict__ Wa,
    const float* __restrict__ Wb, float* __restrict__ Ca, float* __restrict__ Cb,
    int K)
{
  // C[M,128] = A[M,K] @ W[K,128] for two W simultaneously (shared A tile).
  __shared__ float sWa[32][128];
  __shared__ float sWb[32][128];
  __shared__ float sA[64][36];
  const int tid = threadIdx.x;
  const int tx = tid & 15;
  const int ty = tid >> 4;
  const long rowBase = (long)blockIdx.x * TILE_M;

  float accA[4][8];
  float accB[4][8];
#pragma unroll
  for (int i = 0; i < 4; ++i)
#pragma unroll
    for (int j = 0; j < 8; ++j) { accA[i][j] = 0.f; accB[i][j] = 0.f; }

  for (int k0 = 0; k0 < K; k0 += 32) {
#pragma unroll
    for (int i = 0; i < 4; ++i) {
      int f = tid + i * 256;
      int r = f >> 5, c = f & 31;
      *(float4*)(&sWa[r][c * 4]) = *(const float4*)(Wa + (size_t)(k0 + r) * 128 + c * 4);
      *(float4*)(&sWb[r][c * 4]) = *(const float4*)(Wb + (size_t)(k0 + r) * 128 + c * 4);
    }
#pragma unroll
    for (int i = 0; i < 2; ++i) {
      int f = tid + i * 256;
      int r = f >> 3, c = f & 7;
      *(float4*)(&sA[r][c * 4]) = *(const float4*)(A + (rowBase + r) * (size_t)K + k0 + c * 4);
    }
    __syncthreads();
#pragma unroll
    for (int k = 0; k < 32; ++k) {
      float4 wa0 = *(const float4*)(&sWa[k][tx * 8]);
      float4 wa1 = *(const float4*)(&sWa[k][tx * 8 + 4]);
      float4 wb0 = *(const float4*)(&sWb[k][tx * 8]);
      float4 wb1 = *(const float4*)(&sWb[k][tx * 8 + 4]);
#pragma unroll
      for (int i = 0; i < 4; ++i) {
        float a = sA[ty * 4 + i][k];
        accA[i][0] += a * wa0.x; accA[i][1] += a * wa0.y;
        accA[i][2] += a * wa0.z; accA[i][3] += a * wa0.w;
        accA[i][4] += a * wa1.x; accA[i][5] += a * wa1.y;
        accA[i][6] += a * wa1.z; accA[i][7] += a * wa1.w;
        accB[i][0] += a * wb0.x; accB[i][1] += a * wb0.y;
        accB[i][2] += a * wb0.z; accB[i][3] += a * wb0.w;
        accB[i][4] += a * wb1.x; accB[i][5] += a * wb1.y;
        accB[i][6] += a * wb1.z; accB[i][7] += a * wb1.w;
      }
    }
    __syncthreads();
  }
#pragma unroll
  for (int i = 0; i < 4; ++i) {
    long row = rowBase + ty * 4 + i;
    *(float4*)(Ca + row * 128 + tx * 8)     = make_float4(accA[i][0], accA[i][1], accA[i][2], accA[i][3]);
    *(float4*)(Ca + row * 128 + tx * 8 + 4) = make_float4(accA[i][4], accA[i][5], accA[i][6], accA[i][7]);
    *(float4*)(Cb + row * 128 + tx * 8)     = make_float4(accB[i][0], accB[i][1], accB[i][2], accB[i][3]);
    *(float4*)(Cb + row * 128 + tx * 8 + 4) = make_float4(accB[i][4], accB[i][5], accB[i][6], accB[i][7]);
  }
}

// ---------------- CSR build (dst-indexed) ----------------
__global__ void csr_count(const int* __restrict__ dst, int* __restrict__ deg, int E)
{
  int e = blockIdx.x * 256 + threadIdx.x;
  if (e < E) atomicAdd(&deg[dst[e]], 1);
}

// 3-phase multi-block exclusive scan. 1024 elements per block.
// phase 1: per-block totals
__global__ __launch_bounds__(256) void scan_reduce(const int* __restrict__ deg,
                                                   int* __restrict__ bsum, int n)
{
  __shared__ int s[256];
  int b = blockIdx.x, t = threadIdx.x;
  int base = b * 1024;
  int v = 0;
#pragma unroll
  for (int i = 0; i < 4; ++i) {
    int idx = base + t + i * 256;
    if (idx < n) v += deg[idx];
  }
  s[t] = v;
  __syncthreads();
  for (int d = 128; d > 0; d >>= 1) {
    if (t < d) s[t] += s[t + d];
    __syncthreads();
  }
  if (t == 0) bsum[b] = s[0];
}

// phase 2: exclusive scan of block totals (single block, nb <= 1024); stores
// the grand total at bsum[nb].
__global__ __launch_bounds__(1024) void scan_partials(int* __restrict__ bsum, int nb)
{
  __shared__ int s[1024];
  int t = threadIdx.x;
  s[t] = (t < nb) ? bsum[t] : 0;
  __syncthreads();
  for (int d = 1; d < 1024; d <<= 1) {
    int v = (t >= d) ? s[t - d] : 0;
    __syncthreads();
    s[t] += v;
    __syncthreads();
  }
  if (t < nb) bsum[t] = (t == 0) ? 0 : s[t - 1];   // exclusive
  if (t == 1023) bsum[nb] = s[1023];               // total
}

// phase 3: per-block rescan with base; writes off[] AND cur[] (cursor copy).
__global__ __launch_bounds__(256) void scan_final(const int* __restrict__ deg,
                                                  const int* __restrict__ bsum,
                                                  int* __restrict__ off,
                                                  int* __restrict__ cur, int n, int nb)
{
  __shared__ int s[256];
  int b = blockIdx.x, t = threadIdx.x;
  int base = b * 1024 + t * 4;
  int v0 = 0, v1 = 0, v2 = 0, v3 = 0;
  if (base + 0 < n) v0 = deg[base + 0];
  if (base + 1 < n) v1 = deg[base + 1];
  if (base + 2 < n) v2 = deg[base + 2];
  if (base + 3 < n) v3 = deg[base + 3];
  s[t] = v0 + v1 + v2 + v3;
  __syncthreads();
  for (int d = 1; d < 256; d <<= 1) {
    int v = (t >= d) ? s[t - d] : 0;
    __syncthreads();
    s[t] += v;
    __syncthreads();
  }
  int run = bsum[b] + ((t == 0) ? 0 : s[t - 1]);
  if (base + 0 < n) { off[base + 0] = run; cur[base + 0] = run; run += v0; }
  if (base + 1 < n) { off[base + 1] = run; cur[base + 1] = run; run += v1; }
  if (base + 2 < n) { off[base + 2] = run; cur[base + 2] = run; run += v2; }
  if (base + 3 < n) { off[base + 3] = run; cur[base + 3] = run; run += v3; }
  if (b == 0 && t == 0) off[n] = bsum[nb];
}

__global__ void csr_fill(const int* __restrict__ src, const int* __restrict__ dst,
                         int* __restrict__ cur, int* __restrict__ eidx, int E)
{
  int e = blockIdx.x * 256 + threadIdx.x;
  if (e >= E) return;
  int pos = atomicAdd(&cur[dst[e]], 1);
  eidx[pos] = src[e];
}

// ---------------- fused gathers ----------------
// out[r] = relu(pre[r] + sum_{j in [off[r],off[r+1])} msg[eidx[j]])
__global__ __launch_bounds__(256) void gather_add_relu(
    const float* __restrict__ pre, const float* __restrict__ msg,
    const int* __restrict__ off, const int* __restrict__ eidx,
    float* __restrict__ out, int R)
{
  int r = blockIdx.x * 8 + (threadIdx.x >> 5);
  if (r >= R) return;
  int f = (threadIdx.x & 31) * 4;
  float4 acc = ld4(pre + (size_t)r * 128 + f);
  int e1 = off[r + 1];
  for (int j = off[r]; j < e1; ++j) {
    int s = eidx[j];
    float4 m = ld4(msg + (size_t)s * 128 + f);
    acc.x += m.x; acc.y += m.y; acc.z += m.z; acc.w += m.w;
  }
  float4 o = make_float4(fmaxf(acc.x, 0.f), fmaxf(acc.y, 0.f),
                         fmaxf(acc.z, 0.f), fmaxf(acc.w, 0.f));
  *(float4*)(out + (size_t)r * 128 + f) = o;
}

// 2-set layer 0, fully fused: compose self term + gather messages formed on the fly.
__global__ __launch_bounds__(256) void gather_two0(
    const float* __restrict__ HU1, const float* __restrict__ HV1,
    const float* __restrict__ HU2, const float* __restrict__ HV2,
    const float* __restrict__ iso,
    const float* __restrict__ w1iso, const float* __restrict__ w2iso,
    const int* __restrict__ pu, const int* __restrict__ pv,
    const int* __restrict__ off, const int* __restrict__ eidx,
    float* __restrict__ out, int P)
{
  int p = blockIdx.x * 8 + (threadIdx.x >> 5);
  if (p >= P) return;
  int f = (threadIdx.x & 31) * 4;
  float4 wi1 = ld4(w1iso + f);
  float4 wi2 = ld4(w2iso + f);
  int u0 = pu[p], v0 = pv[p];
  float is0 = iso[p];
  float4 a = ld4(HU1 + (size_t)u0 * 128 + f);
  float4 b = ld4(HV1 + (size_t)v0 * 128 + f);
  float4 acc;
  acc.x = a.x + b.x + is0 * wi1.x;
  acc.y = a.y + b.y + is0 * wi1.y;
  acc.z = a.z + b.z + is0 * wi1.z;
  acc.w = a.w + b.w + is0 * wi1.w;
  int e1 = off[p + 1];
  for (int j = off[p]; j < e1; ++j) {
    int s = eidx[j];
    int u = pu[s], v = pv[s];
    float iss = iso[s];
    float4 mu = ld4(HU2 + (size_t)u * 128 + f);
    float4 mv = ld4(HV2 + (size_t)v * 128 + f);
    acc.x += mu.x + mv.x + iss * wi2.x;
    acc.y += mu.y + mv.y + iss * wi2.y;
    acc.z += mu.z + mv.z + iss * wi2.z;
    acc.w += mu.w + mv.w + iss * wi2.w;
  }
  float4 o = make_float4(fmaxf(acc.x, 0.f), fmaxf(acc.y, 0.f),
                         fmaxf(acc.z, 0.f), fmaxf(acc.w, 0.f));
  *(float4*)(out + (size_t)p * 128 + f) = o;
}

// contiguous segment sum (128 wide)
__global__ void seg_sum(const float* __restrict__ X, float* __restrict__ out,
                        int rows_per_seg, int rows_per_chunk)
{
  int g = blockIdx.x, part = blockIdx.y, f = threadIdx.x;
  int r0 = part * rows_per_chunk;
  int r1 = r0 + rows_per_chunk;
  if (r1 > rows_per_seg) r1 = rows_per_seg;
  float s = 0.f;
  for (int i = r0; i < r1; ++i)
    s += X[((size_t)g * rows_per_seg + i) * 128 + f];
  atomicAdd(&out[g * 128 + f], s);
}

__global__ void classifier(const float* __restrict__ ge1, const float* __restrict__ ge2,
                           const float* __restrict__ W0, const float* __restrict__ b0,
                           const float* __restrict__ W1, const float* __restrict__ b1,
                           float* __restrict__ out)
{
  __shared__ float comb[256];
  __shared__ float hc[128];
  int g = blockIdx.x, t = threadIdx.x;  // 128 threads
  comb[t]       = ge1[g * 128 + t];
  comb[t + 128] = ge2[g * 128 + t];
  __syncthreads();
  float s = b0[t];
  for (int k = 0; k < 256; ++k) s += comb[k] * W0[k * 128 + t];
  hc[t] = fmaxf(s, 0.f);
  __syncthreads();
  if (t < 10) {
    float s2 = b1[t];
    for (int k = 0; k < 128; ++k) s2 += hc[k] * W1[k * 10 + t];
    out[g * 10 + t] = s2;
  }
}

extern "C" void kernel_launch(void* const* d_in, const int* in_sizes, int n_in,
                              void* d_out, int out_size, void* d_ws, size_t ws_size,
                              hipStream_t stream)
{
  (void)n_in; (void)out_size; (void)ws_size;
  const float* x       = (const float*)d_in[0];
  const float* g1_W1_0 = (const float*)d_in[1];
  const float* g1_W2_0 = (const float*)d_in[2];
  const float* g1_W1_1 = (const float*)d_in[3];
  const float* g1_W2_1 = (const float*)d_in[4];
  const float* g1_W1_2 = (const float*)d_in[5];
  const float* g1_W2_2 = (const float*)d_in[6];
  const float* k_W1_0  = (const float*)d_in[7];   // [257,128]
  const float* k_W2_0  = (const float*)d_in[8];   // [257,128]
  const float* k_W1_1  = (const float*)d_in[9];   // [128,128]
  const float* k_W2_1  = (const float*)d_in[10];  // [128,128]
  const float* c_W0    = (const float*)d_in[11];
  const float* c_b0    = (const float*)d_in[12];
  const float* c_W1    = (const float*)d_in[13];
  const float* c_b1    = (const float*)d_in[14];
  const float* iso     = (const float*)d_in[15];  // [P]
  const int*   ei      = (const int*)d_in[16];    // [2,E1]
  const int*   pu      = (const int*)d_in[18];    // [P]
  const int*   pv      = (const int*)d_in[19];    // [P]
  const int*   te      = (const int*)d_in[20];    // [2,E2]

  const int N  = in_sizes[0] / 64;   // 4096
  const int E1 = in_sizes[16] / 2;
  const int P  = in_sizes[18];       // 129024
  const int E2 = in_sizes[20] / 2;
  const int B  = 64;
  const int ppg = P / B;             // 2016

  const size_t NH = (size_t)N * 128;
  const size_t PH = (size_t)P * 128;

  float* ws   = (float*)d_ws;
  float* h    = ws;              // NH
  float* preN = h    + NH;       // NH
  float* msgN = preN + NH;       // NH
  float* HU1  = msgN + NH;       // NH
  float* HV1  = HU1  + NH;       // NH
  float* HU2  = HV1  + NH;       // NH
  float* HV2  = HU2  + NH;       // NH
  float* ge1  = HV2  + NH;       // 8192
  float* ge2  = ge1  + 8192;     // 8192
  float* H2   = ge2  + 8192;     // PH
  float* PRE2 = H2   + PH;       // PH
  float* MSG2 = PRE2 + PH;       // PH

  int* ip    = (int*)(MSG2 + PH);
  int* degN  = ip;               // N
  int* offN  = degN + N;         // N+1
  int* curN  = offN + N + 1;     // N
  int* eidxN = curN + N;         // E1
  int* degP  = eidxN + E1;       // P
  int* offP  = degP + P;         // P+1
  int* curP  = offP + P + 1;     // P
  int* eidxP = curP + P;         // E2
  int* bsumN = eidxP + E2;       // nbN+1
  int* bsumP = bsumN + 8;        // nbP+1

  const int gemmBlocksN = N / TILE_M;        // 64
  const int gemmBlocksP = P / TILE_M;        // 2016
  const int gatherN = (N + 7) / 8;
  const int gatherP = (P + 7) / 8;
  const int nbN = (N + 1023) / 1024;         // 4
  const int nbP = (P + 1023) / 1024;         // 126

  // ---- build CSRs (node graph + pair graph) ----
  hipMemsetAsync(degN, 0, (size_t)N * 4, stream);
  hipMemsetAsync(degP, 0, (size_t)P * 4, stream);
  csr_count<<<(E1 + 255) / 256, 256, 0, stream>>>(ei + E1, degN, E1);
  csr_count<<<(E2 + 255) / 256, 256, 0, stream>>>(te + E2, degP, E2);
  scan_reduce<<<nbN, 256, 0, stream>>>(degN, bsumN, N);
  scan_reduce<<<nbP, 256, 0, stream>>>(degP, bsumP, P);
  scan_partials<<<1, 1024, 0, stream>>>(bsumN, nbN);
  scan_partials<<<1, 1024, 0, stream>>>(bsumP, nbP);
  scan_final<<<nbN, 256, 0, stream>>>(degN, bsumN, offN, curN, N, nbN);
  scan_final<<<nbP, 256, 0, stream>>>(degP, bsumP, offP, curP, P, nbP);
  csr_fill<<<(E1 + 255) / 256, 256, 0, stream>>>(ei, ei + E1, curN, eidxN, E1);
  csr_fill<<<(E2 + 255) / 256, 256, 0, stream>>>(te, te + E2, curP, eidxP, E2);

  // ---- node stage: 3 MP layers (gemm + fused gather/relu) ----
  gemm_dual_n128<<<gemmBlocksN, 256, 0, stream>>>(x, g1_W1_0, g1_W2_0, preN, msgN, 64);
  gather_add_relu<<<gatherN, 256, 0, stream>>>(preN, msgN, offN, eidxN, h, N);
  gemm_dual_n128<<<gemmBlocksN, 256, 0, stream>>>(h, g1_W1_1, g1_W2_1, preN, msgN, 128);
  gather_add_relu<<<gatherN, 256, 0, stream>>>(preN, msgN, offN, eidxN, h, N);
  gemm_dual_n128<<<gemmBlocksN, 256, 0, stream>>>(h, g1_W1_2, g1_W2_2, preN, msgN, 128);
  gather_add_relu<<<gatherN, 256, 0, stream>>>(preN, msgN, offN, eidxN, h, N);

  // graph_emb_1
  hipMemsetAsync(ge1, 0, 8192 * 4, stream);
  seg_sum<<<dim3(B, 1), 128, 0, stream>>>(h, ge1, 64, 64);

  // ---- 2-set stage ----
  gemm_dual_n128<<<gemmBlocksN, 256, 0, stream>>>(h, k_W1_0,             k_W2_0,             HU1, HU2, 128);
  gemm_dual_n128<<<gemmBlocksN, 256, 0, stream>>>(h, k_W1_0 + 128 * 128, k_W2_0 + 128 * 128, HV1, HV2, 128);

  // layer k0: fully fused gather (no atomics, no memset, no compose pass)
  gather_two0<<<gatherP, 256, 0, stream>>>(HU1, HV1, HU2, HV2, iso,
                                           k_W1_0 + 256 * 128, k_W2_0 + 256 * 128,
                                           pu, pv, offP, eidxP, H2, P);

  // layer k1: dual big GEMM (pre into PRE2, msg into MSG2), fused gather
  gemm_dual_n128<<<gemmBlocksP, 256, 0, stream>>>(H2, k_W1_1, k_W2_1, PRE2, MSG2, 128);
  gather_add_relu<<<gatherP, 256, 0, stream>>>(PRE2, MSG2, offP, eidxP, H2, P);

  // graph_emb_2
  hipMemsetAsync(ge2, 0, 8192 * 4, stream);
  seg_sum<<<dim3(B, 16), 128, 0, stream>>>(H2, ge2, ppg, (ppg + 15) / 16);

  // classifier
  classifier<<<B, 128, 0, stream>>>(ge1, ge2, c_W0, c_b0, c_W1, c_b1, (float*)d_out);
}

// Round 4
// 436.766 us; speedup vs baseline: 1.7896x; 1.2602x over previous
//
#include <hip/hip_runtime.h>
#include <hip/hip_bf16.h>

// Hierarchical 1-2-GNN forward. B=64 graphs x 64 nodes, P=129024 pairs, HID=128.
// Round 4: all dual GEMMs -> MFMA bf16 (16x16x32), weights pre-swizzled to
// B-fragment layout once (K-loop reads W-frags from L2, no LDS/barriers in the
// hot loop; A-frags global->VGPR). Whole pipeline carries bf16 values with
// fp32 accumulation; P-stage HBM traffic halves.

typedef short s16x8 __attribute__((ext_vector_type(8)));
typedef float f32x4 __attribute__((ext_vector_type(4)));

__device__ __forceinline__ unsigned short f2bf(float f) {
  union { float f; unsigned u; } x; x.f = f;
  unsigned r = (x.u + 0x7fffu + ((x.u >> 16) & 1u)) >> 16;   // RNE
  return (unsigned short)r;
}
__device__ __forceinline__ float bf2f(unsigned short h) {
  union { unsigned u; float f; } x; x.u = ((unsigned)h) << 16;
  return x.f;
}
__device__ __forceinline__ float4 ldbf4(const unsigned short* p) {
  ushort4 q = *(const ushort4*)p;
  return make_float4(bf2f(q.x), bf2f(q.y), bf2f(q.z), bf2f(q.w));
}
__device__ __forceinline__ void stbf4(unsigned short* p, float4 v) {
  ushort4 q;
  q.x = f2bf(v.x); q.y = f2bf(v.y); q.z = f2bf(v.z); q.w = f2bf(v.w);
  *(ushort4*)p = q;
}
__device__ __forceinline__ float4 ld4(const float* p) { return *(const float4*)p; }

// ---------------- dtype conversion ----------------
__global__ void convert_f2b(const float* __restrict__ src,
                            unsigned short* __restrict__ dst, int n4)
{
  int i = blockIdx.x * 256 + threadIdx.x;
  if (i >= n4) return;
  stbf4(dst + (size_t)i * 4, ld4(src + (size_t)i * 4));
}

// ---------------- weight pre-swizzle into MFMA B-fragment order ----------------
// frag f = ((wsel*8 + ntile)*kcs + kc)*64 + lane holds 8 bf16:
//   W[k][n], k = kc*32 + (lane>>4)*8 + j, n = ntile*16 + (lane&15)
struct SwzArgs {
  const float* wa[6];
  const float* wb[6];
  unsigned short* dst[6];
  int kclog[6];
};

__global__ void swizzle_weights(SwzArgs args)
{
  int p = blockIdx.y;
  int kclog = args.kclog[p];
  int kcs = 1 << kclog;
  int total = (16 * kcs) << 6;             // 2*8*kcs*64 fragments
  int f = blockIdx.x * 256 + threadIdx.x;
  if (f >= total) return;
  int lane = f & 63;
  int t1 = f >> 6;
  int kc = t1 & (kcs - 1);
  int t2 = t1 >> kclog;
  int nt = t2 & 7;
  int wsel = t2 >> 3;
  const float* W = wsel ? args.wb[p] : args.wa[p];
  int k0 = kc * 32 + ((lane >> 4) << 3);
  int n = nt * 16 + (lane & 15);
  unsigned short tmp[8];
#pragma unroll
  for (int j = 0; j < 8; ++j) tmp[j] = f2bf(W[(size_t)(k0 + j) * 128 + n]);
  *(uint4*)(args.dst[p] + (size_t)f * 8) = *(uint4*)tmp;
}

// ---------------- dual MFMA GEMM: C[M,128] = A[M,K]@W[K,128] for two W ----------------
// 256 threads = 4 waves; tile 64 rows; wave w owns rows w*16..w*16+15.
// No LDS in K-loop: A-frags global->VGPR, W-frags from (L2-resident) Wfrag.
template<int KCS>
__global__ __launch_bounds__(256) void gemm_dual_mfma(
    const unsigned short* __restrict__ A, const unsigned short* __restrict__ Wfrag,
    unsigned short* __restrict__ Ca, unsigned short* __restrict__ Cb)
{
  const int K = KCS * 32;
  const int tid = threadIdx.x;
  const int lane = tid & 63;
  const int wv = tid >> 6;
  const long rowBase = (long)blockIdx.x * 64;

  f32x4 accA[8], accB[8];
#pragma unroll
  for (int i = 0; i < 8; ++i) {
    accA[i] = (f32x4)0.0f;
    accB[i] = (f32x4)0.0f;
  }

  const unsigned short* aptr =
      A + (size_t)(rowBase + wv * 16 + (lane & 15)) * K + ((lane >> 4) << 3);
  const unsigned short* wptr = Wfrag + (size_t)lane * 8;

#pragma unroll
  for (int kc = 0; kc < KCS; ++kc) {
    s16x8 af = *(const s16x8*)(aptr + kc * 32);
#pragma unroll
    for (int nt = 0; nt < 8; ++nt) {
      s16x8 b0 = *(const s16x8*)(wptr + ((size_t)((0 * 8 + nt) * KCS + kc) << 9));
      s16x8 b1 = *(const s16x8*)(wptr + ((size_t)((1 * 8 + nt) * KCS + kc) << 9));
      accA[nt] = __builtin_amdgcn_mfma_f32_16x16x32_bf16(af, b0, accA[nt], 0, 0, 0);
      accB[nt] = __builtin_amdgcn_mfma_f32_16x16x32_bf16(af, b1, accB[nt], 0, 0, 0);
    }
  }

  // epilogue: repack D (col=lane&15, row=quad*4+reg) through LDS -> coalesced b128 stores
  __shared__ unsigned short sOut[64][136];   // +8 pad: break power-of-2 row stride
  const int colb = lane & 15;
  const int row0 = wv * 16 + ((lane >> 4) << 2);
#pragma unroll
  for (int sel = 0; sel < 2; ++sel) {
    __syncthreads();
#pragma unroll
    for (int nt = 0; nt < 8; ++nt) {
      f32x4 v = sel ? accB[nt] : accA[nt];
#pragma unroll
      for (int r = 0; r < 4; ++r)
        sOut[row0 + r][nt * 16 + colb] = f2bf(v[r]);
    }
    __syncthreads();
    unsigned short* C = sel ? Cb : Ca;
#pragma unroll
    for (int i = 0; i < 4; ++i) {
      int fi = tid + i * 256;
      int row = fi >> 4;
      int c8 = fi & 15;
      *(uint4*)(C + (rowBase + row) * 128 + c8 * 8) = *(uint4*)&sOut[row][c8 * 8];
    }
  }
}

// ---------------- CSR build (dst-indexed) ----------------
__global__ void csr_count(const int* __restrict__ dst, int* __restrict__ deg, int E)
{
  int e = blockIdx.x * 256 + threadIdx.x;
  if (e < E) atomicAdd(&deg[dst[e]], 1);
}

__global__ __launch_bounds__(256) void scan_reduce(const int* __restrict__ deg,
                                                   int* __restrict__ bsum, int n)
{
  __shared__ int s[256];
  int b = blockIdx.x, t = threadIdx.x;
  int base = b * 1024;
  int v = 0;
#pragma unroll
  for (int i = 0; i < 4; ++i) {
    int idx = base + t + i * 256;
    if (idx < n) v += deg[idx];
  }
  s[t] = v;
  __syncthreads();
  for (int d = 128; d > 0; d >>= 1) {
    if (t < d) s[t] += s[t + d];
    __syncthreads();
  }
  if (t == 0) bsum[b] = s[0];
}

__global__ __launch_bounds__(1024) void scan_partials(int* __restrict__ bsum, int nb)
{
  __shared__ int s[1024];
  int t = threadIdx.x;
  s[t] = (t < nb) ? bsum[t] : 0;
  __syncthreads();
  for (int d = 1; d < 1024; d <<= 1) {
    int v = (t >= d) ? s[t - d] : 0;
    __syncthreads();
    s[t] += v;
    __syncthreads();
  }
  if (t < nb) bsum[t] = (t == 0) ? 0 : s[t - 1];
  if (t == 1023) bsum[nb] = s[1023];
}

__global__ __launch_bounds__(256) void scan_final(const int* __restrict__ deg,
                                                  const int* __restrict__ bsum,
                                                  int* __restrict__ off,
                                                  int* __restrict__ cur, int n, int nb)
{
  __shared__ int s[256];
  int b = blockIdx.x, t = threadIdx.x;
  int base = b * 1024 + t * 4;
  int v0 = 0, v1 = 0, v2 = 0, v3 = 0;
  if (base + 0 < n) v0 = deg[base + 0];
  if (base + 1 < n) v1 = deg[base + 1];
  if (base + 2 < n) v2 = deg[base + 2];
  if (base + 3 < n) v3 = deg[base + 3];
  s[t] = v0 + v1 + v2 + v3;
  __syncthreads();
  for (int d = 1; d < 256; d <<= 1) {
    int v = (t >= d) ? s[t - d] : 0;
    __syncthreads();
    s[t] += v;
    __syncthreads();
  }
  int run = bsum[b] + ((t == 0) ? 0 : s[t - 1]);
  if (base + 0 < n) { off[base + 0] = run; cur[base + 0] = run; run += v0; }
  if (base + 1 < n) { off[base + 1] = run; cur[base + 1] = run; run += v1; }
  if (base + 2 < n) { off[base + 2] = run; cur[base + 2] = run; run += v2; }
  if (base + 3 < n) { off[base + 3] = run; cur[base + 3] = run; run += v3; }
  if (b == 0 && t == 0) off[n] = bsum[nb];
}

__global__ void csr_fill(const int* __restrict__ src, const int* __restrict__ dst,
                         int* __restrict__ cur, int* __restrict__ eidx, int E)
{
  int e = blockIdx.x * 256 + threadIdx.x;
  if (e >= E) return;
  int pos = atomicAdd(&cur[dst[e]], 1);
  eidx[pos] = src[e];
}

// ---------------- fused gathers (bf16 in / bf16 out, fp32 accumulate) ----------------
__global__ __launch_bounds__(256) void gather_add_relu_bf(
    const unsigned short* __restrict__ pre, const unsigned short* __restrict__ msg,
    const int* __restrict__ off, const int* __restrict__ eidx,
    unsigned short* __restrict__ out, int R)
{
  int r = blockIdx.x * 8 + (threadIdx.x >> 5);
  if (r >= R) return;
  int f = (threadIdx.x & 31) * 4;
  float4 acc = ldbf4(pre + (size_t)r * 128 + f);
  int e1 = off[r + 1];
  for (int j = off[r]; j < e1; ++j) {
    int s = eidx[j];
    float4 m = ldbf4(msg + (size_t)s * 128 + f);
    acc.x += m.x; acc.y += m.y; acc.z += m.z; acc.w += m.w;
  }
  stbf4(out + (size_t)r * 128 + f,
        make_float4(fmaxf(acc.x, 0.f), fmaxf(acc.y, 0.f),
                    fmaxf(acc.z, 0.f), fmaxf(acc.w, 0.f)));
}

__global__ __launch_bounds__(256) void gather_two0_bf(
    const unsigned short* __restrict__ HU1, const unsigned short* __restrict__ HV1,
    const unsigned short* __restrict__ HU2, const unsigned short* __restrict__ HV2,
    const float* __restrict__ iso,
    const float* __restrict__ w1iso, const float* __restrict__ w2iso,
    const int* __restrict__ pu, const int* __restrict__ pv,
    const int* __restrict__ off, const int* __restrict__ eidx,
    unsigned short* __restrict__ out, int P)
{
  int p = blockIdx.x * 8 + (threadIdx.x >> 5);
  if (p >= P) return;
  int f = (threadIdx.x & 31) * 4;
  float4 wi1 = ld4(w1iso + f);
  float4 wi2 = ld4(w2iso + f);
  int u0 = pu[p], v0 = pv[p];
  float is0 = iso[p];
  float4 a = ldbf4(HU1 + (size_t)u0 * 128 + f);
  float4 b = ldbf4(HV1 + (size_t)v0 * 128 + f);
  float4 acc;
  acc.x = a.x + b.x + is0 * wi1.x;
  acc.y = a.y + b.y + is0 * wi1.y;
  acc.z = a.z + b.z + is0 * wi1.z;
  acc.w = a.w + b.w + is0 * wi1.w;
  int e1 = off[p + 1];
  for (int j = off[p]; j < e1; ++j) {
    int s = eidx[j];
    int u = pu[s], v = pv[s];
    float iss = iso[s];
    float4 mu = ldbf4(HU2 + (size_t)u * 128 + f);
    float4 mv = ldbf4(HV2 + (size_t)v * 128 + f);
    acc.x += mu.x + mv.x + iss * wi2.x;
    acc.y += mu.y + mv.y + iss * wi2.y;
    acc.z += mu.z + mv.z + iss * wi2.z;
    acc.w += mu.w + mv.w + iss * wi2.w;
  }
  stbf4(out + (size_t)p * 128 + f,
        make_float4(fmaxf(acc.x, 0.f), fmaxf(acc.y, 0.f),
                    fmaxf(acc.z, 0.f), fmaxf(acc.w, 0.f)));
}

// contiguous segment sum (128 wide), bf16 input
__global__ void seg_sum_bf(const unsigned short* __restrict__ X, float* __restrict__ out,
                           int rows_per_seg, int rows_per_chunk)
{
  int g = blockIdx.x, part = blockIdx.y, f = threadIdx.x;
  int r0 = part * rows_per_chunk;
  int r1 = r0 + rows_per_chunk;
  if (r1 > rows_per_seg) r1 = rows_per_seg;
  float s = 0.f;
  for (int i = r0; i < r1; ++i)
    s += bf2f(X[((size_t)g * rows_per_seg + i) * 128 + f]);
  atomicAdd(&out[g * 128 + f], s);
}

__global__ void classifier(const float* __restrict__ ge1, const float* __restrict__ ge2,
                           const float* __restrict__ W0, const float* __restrict__ b0,
                           const float* __restrict__ W1, const float* __restrict__ b1,
                           float* __restrict__ out)
{
  __shared__ float comb[256];
  __shared__ float hc[128];
  int g = blockIdx.x, t = threadIdx.x;  // 128 threads
  comb[t]       = ge1[g * 128 + t];
  comb[t + 128] = ge2[g * 128 + t];
  __syncthreads();
  float s = b0[t];
  for (int k = 0; k < 256; ++k) s += comb[k] * W0[k * 128 + t];
  hc[t] = fmaxf(s, 0.f);
  __syncthreads();
  if (t < 10) {
    float s2 = b1[t];
    for (int k = 0; k < 128; ++k) s2 += hc[k] * W1[k * 10 + t];
    out[g * 10 + t] = s2;
  }
}

extern "C" void kernel_launch(void* const* d_in, const int* in_sizes, int n_in,
                              void* d_out, int out_size, void* d_ws, size_t ws_size,
                              hipStream_t stream)
{
  (void)n_in; (void)out_size; (void)ws_size;
  const float* x       = (const float*)d_in[0];
  const float* g1_W1_0 = (const float*)d_in[1];
  const float* g1_W2_0 = (const float*)d_in[2];
  const float* g1_W1_1 = (const float*)d_in[3];
  const float* g1_W2_1 = (const float*)d_in[4];
  const float* g1_W1_2 = (const float*)d_in[5];
  const float* g1_W2_2 = (const float*)d_in[6];
  const float* k_W1_0  = (const float*)d_in[7];   // [257,128]
  const float* k_W2_0  = (const float*)d_in[8];   // [257,128]
  const float* k_W1_1  = (const float*)d_in[9];   // [128,128]
  const float* k_W2_1  = (const float*)d_in[10];  // [128,128]
  const float* c_W0    = (const float*)d_in[11];
  const float* c_b0    = (const float*)d_in[12];
  const float* c_W1    = (const float*)d_in[13];
  const float* c_b1    = (const float*)d_in[14];
  const float* iso     = (const float*)d_in[15];  // [P]
  const int*   ei      = (const int*)d_in[16];    // [2,E1]
  const int*   pu      = (const int*)d_in[18];    // [P]
  const int*   pv      = (const int*)d_in[19];    // [P]
  const int*   te      = (const int*)d_in[20];    // [2,E2]

  const int N  = in_sizes[0] / 64;   // 4096
  const int E1 = in_sizes[16] / 2;
  const int P  = in_sizes[18];       // 129024
  const int E2 = in_sizes[20] / 2;
  const int B  = 64;
  const int ppg = P / B;             // 2016

  const size_t NH = (size_t)N * 128;
  const size_t PH = (size_t)P * 128;

  float* ge1 = (float*)d_ws;          // 8192
  float* ge2 = ge1 + 8192;            // 8192
  unsigned short* xb   = (unsigned short*)(ge2 + 8192);  // N*64
  unsigned short* hb   = xb + (size_t)N * 64;  // NH
  unsigned short* preN = hb + NH;              // NH
  unsigned short* msgN = preN + NH;            // NH
  unsigned short* HU1  = msgN + NH;            // NH
  unsigned short* HV1  = HU1 + NH;             // NH
  unsigned short* HU2  = HV1 + NH;             // NH
  unsigned short* HV2  = HU2 + NH;             // NH
  unsigned short* H2   = HV2 + NH;             // PH
  unsigned short* PRE2 = H2 + PH;              // PH
  unsigned short* MSG2 = PRE2 + PH;            // PH
  unsigned short* Wf0  = MSG2 + PH;            // 16384 (K=64)
  unsigned short* Wf1  = Wf0 + 16384;          // 32768
  unsigned short* Wf2  = Wf1 + 32768;
  unsigned short* Wf3  = Wf2 + 32768;
  unsigned short* Wf4  = Wf3 + 32768;
  unsigned short* Wf5  = Wf4 + 32768;

  int* degN  = (int*)(Wf5 + 32768);  // N
  int* offN  = degN + N;             // N+1
  int* curN  = offN + N + 1;         // N
  int* eidxN = curN + N;             // E1
  int* degP  = eidxN + E1;           // P
  int* offP  = degP + P;             // P+1
  int* curP  = offP + P + 1;         // P
  int* eidxP = curP + P;             // E2
  int* bsumN = eidxP + E2;           // nbN+1
  int* bsumP = bsumN + 8;            // nbP+1

  const int gatherN = (N + 7) / 8;
  const int gatherP = (P + 7) / 8;
  const int nbN = (N + 1023) / 1024;   // 4
  const int nbP = (P + 1023) / 1024;   // 126

  // ---- dtype prep ----
  convert_f2b<<<(N * 64 / 4 + 255) / 256, 256, 0, stream>>>(x, xb, N * 64 / 4);
  SwzArgs sa;
  sa.wa[0] = g1_W1_0;           sa.wb[0] = g1_W2_0;           sa.dst[0] = Wf0; sa.kclog[0] = 1;
  sa.wa[1] = g1_W1_1;           sa.wb[1] = g1_W2_1;           sa.dst[1] = Wf1; sa.kclog[1] = 2;
  sa.wa[2] = g1_W1_2;           sa.wb[2] = g1_W2_2;           sa.dst[2] = Wf2; sa.kclog[2] = 2;
  sa.wa[3] = k_W1_0;            sa.wb[3] = k_W2_0;            sa.dst[3] = Wf3; sa.kclog[3] = 2;
  sa.wa[4] = k_W1_0 + 128*128;  sa.wb[4] = k_W2_0 + 128*128;  sa.dst[4] = Wf4; sa.kclog[4] = 2;
  sa.wa[5] = k_W1_1;            sa.wb[5] = k_W2_1;            sa.dst[5] = Wf5; sa.kclog[5] = 2;
  swizzle_weights<<<dim3(16, 6), 256, 0, stream>>>(sa);

  // ---- build CSRs ----
  hipMemsetAsync(degN, 0, (size_t)N * 4, stream);
  hipMemsetAsync(degP, 0, (size_t)P * 4, stream);
  csr_count<<<(E1 + 255) / 256, 256, 0, stream>>>(ei + E1, degN, E1);
  csr_count<<<(E2 + 255) / 256, 256, 0, stream>>>(te + E2, degP, E2);
  scan_reduce<<<nbN, 256, 0, stream>>>(degN, bsumN, N);
  scan_reduce<<<nbP, 256, 0, stream>>>(degP, bsumP, P);
  scan_partials<<<1, 1024, 0, stream>>>(bsumN, nbN);
  scan_partials<<<1, 1024, 0, stream>>>(bsumP, nbP);
  scan_final<<<nbN, 256, 0, stream>>>(degN, bsumN, offN, curN, N, nbN);
  scan_final<<<nbP, 256, 0, stream>>>(degP, bsumP, offP, curP, P, nbP);
  csr_fill<<<(E1 + 255) / 256, 256, 0, stream>>>(ei, ei + E1, curN, eidxN, E1);
  csr_fill<<<(E2 + 255) / 256, 256, 0, stream>>>(te, te + E2, curP, eidxP, E2);

  // ---- node stage: 3 MP layers ----
  gemm_dual_mfma<2><<<N / 64, 256, 0, stream>>>(xb, Wf0, preN, msgN);
  gather_add_relu_bf<<<gatherN, 256, 0, stream>>>(preN, msgN, offN, eidxN, hb, N);
  gemm_dual_mfma<4><<<N / 64, 256, 0, stream>>>(hb, Wf1, preN, msgN);
  gather_add_relu_bf<<<gatherN, 256, 0, stream>>>(preN, msgN, offN, eidxN, hb, N);
  gemm_dual_mfma<4><<<N / 64, 256, 0, stream>>>(hb, Wf2, preN, msgN);
  gather_add_relu_bf<<<gatherN, 256, 0, stream>>>(preN, msgN, offN, eidxN, hb, N);

  // graph_emb_1
  hipMemsetAsync(ge1, 0, 8192 * 4, stream);
  seg_sum_bf<<<dim3(B, 1), 128, 0, stream>>>(hb, ge1, 64, 64);

  // ---- 2-set stage ----
  gemm_dual_mfma<4><<<N / 64, 256, 0, stream>>>(hb, Wf3, HU1, HU2);
  gemm_dual_mfma<4><<<N / 64, 256, 0, stream>>>(hb, Wf4, HV1, HV2);

  gather_two0_bf<<<gatherP, 256, 0, stream>>>(HU1, HV1, HU2, HV2, iso,
                                              k_W1_0 + 256 * 128, k_W2_0 + 256 * 128,
                                              pu, pv, offP, eidxP, H2, P);

  gemm_dual_mfma<4><<<P / 64, 256, 0, stream>>>(H2, Wf5, PRE2, MSG2);
  gather_add_relu_bf<<<gatherP, 256, 0, stream>>>(PRE2, MSG2, offP, eidxP, H2, P);

  // graph_emb_2
  hipMemsetAsync(ge2, 0, 8192 * 4, stream);
  seg_sum_bf<<<dim3(B, 16), 128, 0, stream>>>(H2, ge2, ppg, (ppg + 15) / 16);

  // classifier
  classifier<<<B, 128, 0, stream>>>(ge1, ge2, c_W0, c_b0, c_W1, c_b1, (float*)d_out);
}

// Round 5
// 382.764 us; speedup vs baseline: 2.0421x; 1.1411x over previous
//
#include <hip/hip_runtime.h>
#include <hip/hip_bf16.h>

// Hierarchical 1-2-GNN forward. B=64 graphs x 64 nodes, P=129024 pairs, HID=128.
// Round 5: latency attack on the pair-graph gathers:
//  - csr_fill packs per-edge records (u, v, iso, src) -> one broadcast int4 load
//    replaces a 3-level dependent chain with 2 levels
//  - edge loops unrolled x2 (independent loads, 2x MLP; avg degree ~1.9)
//  - CSR build merged: 1 memset + 5 kernels (was 2 + 12)

typedef short s16x8 __attribute__((ext_vector_type(8)));
typedef float f32x4 __attribute__((ext_vector_type(4)));

__device__ __forceinline__ unsigned short f2bf(float f) {
  union { float f; unsigned u; } x; x.f = f;
  unsigned r = (x.u + 0x7fffu + ((x.u >> 16) & 1u)) >> 16;   // RNE
  return (unsigned short)r;
}
__device__ __forceinline__ float bf2f(unsigned short h) {
  union { unsigned u; float f; } x; x.u = ((unsigned)h) << 16;
  return x.f;
}
__device__ __forceinline__ float4 ldbf4(const unsigned short* p) {
  ushort4 q = *(const ushort4*)p;
  return make_float4(bf2f(q.x), bf2f(q.y), bf2f(q.z), bf2f(q.w));
}
__device__ __forceinline__ void stbf4(unsigned short* p, float4 v) {
  ushort4 q;
  q.x = f2bf(v.x); q.y = f2bf(v.y); q.z = f2bf(v.z); q.w = f2bf(v.w);
  *(ushort4*)p = q;
}
__device__ __forceinline__ float4 ld4(const float* p) { return *(const float4*)p; }

// ---------------- dtype conversion ----------------
__global__ void convert_f2b(const float* __restrict__ src,
                            unsigned short* __restrict__ dst, int n4)
{
  int i = blockIdx.x * 256 + threadIdx.x;
  if (i >= n4) return;
  stbf4(dst + (size_t)i * 4, ld4(src + (size_t)i * 4));
}

// ---------------- weight pre-swizzle into MFMA B-fragment order ----------------
struct SwzArgs {
  const float* wa[6];
  const float* wb[6];
  unsigned short* dst[6];
  int kclog[6];
};

__global__ void swizzle_weights(SwzArgs args)
{
  int p = blockIdx.y;
  int kclog = args.kclog[p];
  int kcs = 1 << kclog;
  int total = (16 * kcs) << 6;
  int f = blockIdx.x * 256 + threadIdx.x;
  if (f >= total) return;
  int lane = f & 63;
  int t1 = f >> 6;
  int kc = t1 & (kcs - 1);
  int t2 = t1 >> kclog;
  int nt = t2 & 7;
  int wsel = t2 >> 3;
  const float* W = wsel ? args.wb[p] : args.wa[p];
  int k0 = kc * 32 + ((lane >> 4) << 3);
  int n = nt * 16 + (lane & 15);
  unsigned short tmp[8];
#pragma unroll
  for (int j = 0; j < 8; ++j) tmp[j] = f2bf(W[(size_t)(k0 + j) * 128 + n]);
  *(uint4*)(args.dst[p] + (size_t)f * 8) = *(uint4*)tmp;
}

// ---------------- dual MFMA GEMM ----------------
template<int KCS>
__global__ __launch_bounds__(256) void gemm_dual_mfma(
    const unsigned short* __restrict__ A, const unsigned short* __restrict__ Wfrag,
    unsigned short* __restrict__ Ca, unsigned short* __restrict__ Cb)
{
  const int K = KCS * 32;
  const int tid = threadIdx.x;
  const int lane = tid & 63;
  const int wv = tid >> 6;
  const long rowBase = (long)blockIdx.x * 64;

  f32x4 accA[8], accB[8];
#pragma unroll
  for (int i = 0; i < 8; ++i) {
    accA[i] = (f32x4)0.0f;
    accB[i] = (f32x4)0.0f;
  }

  const unsigned short* aptr =
      A + (size_t)(rowBase + wv * 16 + (lane & 15)) * K + ((lane >> 4) << 3);
  const unsigned short* wptr = Wfrag + (size_t)lane * 8;

#pragma unroll
  for (int kc = 0; kc < KCS; ++kc) {
    s16x8 af = *(const s16x8*)(aptr + kc * 32);
#pragma unroll
    for (int nt = 0; nt < 8; ++nt) {
      s16x8 b0 = *(const s16x8*)(wptr + ((size_t)((0 * 8 + nt) * KCS + kc) << 9));
      s16x8 b1 = *(const s16x8*)(wptr + ((size_t)((1 * 8 + nt) * KCS + kc) << 9));
      accA[nt] = __builtin_amdgcn_mfma_f32_16x16x32_bf16(af, b0, accA[nt], 0, 0, 0);
      accB[nt] = __builtin_amdgcn_mfma_f32_16x16x32_bf16(af, b1, accB[nt], 0, 0, 0);
    }
  }

  __shared__ unsigned short sOut[64][136];
  const int colb = lane & 15;
  const int row0 = wv * 16 + ((lane >> 4) << 2);
#pragma unroll
  for (int sel = 0; sel < 2; ++sel) {
    __syncthreads();
#pragma unroll
    for (int nt = 0; nt < 8; ++nt) {
      f32x4 v = sel ? accB[nt] : accA[nt];
#pragma unroll
      for (int r = 0; r < 4; ++r)
        sOut[row0 + r][nt * 16 + colb] = f2bf(v[r]);
    }
    __syncthreads();
    unsigned short* C = sel ? Cb : Ca;
#pragma unroll
    for (int i = 0; i < 4; ++i) {
      int fi = tid + i * 256;
      int row = fi >> 4;
      int c8 = fi & 15;
      *(uint4*)(C + (rowBase + row) * 128 + c8 * 8) = *(uint4*)&sOut[row][c8 * 8];
    }
  }
}

// ---------------- merged CSR build (dst-indexed, node graph + pair graph) ----------------
__global__ void csr_count_both(const int* __restrict__ dstN, int E1,
                               const int* __restrict__ dstP, int E2,
                               int* __restrict__ degN, int* __restrict__ degP)
{
  int e = blockIdx.x * 256 + threadIdx.x;
  if (e < E1) atomicAdd(&degN[dstN[e]], 1);
  else if (e < E1 + E2) atomicAdd(&degP[dstP[e - E1]], 1);
}

__global__ __launch_bounds__(256) void scan_reduce_both(
    const int* __restrict__ degP, int nP, const int* __restrict__ degN, int nN,
    int* __restrict__ bsumP, int* __restrict__ bsumN, int nbP)
{
  __shared__ int s[256];
  int b = blockIdx.x, t = threadIdx.x;
  const int* deg; int n; int* bs;
  if (b < nbP) { deg = degP; n = nP; bs = bsumP; }
  else { deg = degN; n = nN; bs = bsumN; b -= nbP; }
  int base = b * 1024;
  int v = 0;
#pragma unroll
  for (int i = 0; i < 4; ++i) {
    int idx = base + t + i * 256;
    if (idx < n) v += deg[idx];
  }
  s[t] = v;
  __syncthreads();
  for (int d = 128; d > 0; d >>= 1) {
    if (t < d) s[t] += s[t + d];
    __syncthreads();
  }
  if (t == 0) bs[b] = s[0];
}

__global__ __launch_bounds__(1024) void scan_partials_both(
    int* __restrict__ bsumP, int nbP, int* __restrict__ bsumN, int nbN)
{
  __shared__ int s[1024];
  int* bsum; int nb;
  if (blockIdx.x == 0) { bsum = bsumP; nb = nbP; }
  else { bsum = bsumN; nb = nbN; }
  int t = threadIdx.x;
  s[t] = (t < nb) ? bsum[t] : 0;
  __syncthreads();
  for (int d = 1; d < 1024; d <<= 1) {
    int v = (t >= d) ? s[t - d] : 0;
    __syncthreads();
    s[t] += v;
    __syncthreads();
  }
  if (t < nb) bsum[t] = (t == 0) ? 0 : s[t - 1];
  if (t == 1023) bsum[nb] = s[1023];
}

__global__ __launch_bounds__(256) void scan_final_both(
    const int* __restrict__ degP, const int* __restrict__ bsumP,
    int* __restrict__ offP, int* __restrict__ curP, int nP,
    const int* __restrict__ degN, const int* __restrict__ bsumN,
    int* __restrict__ offN, int* __restrict__ curN, int nN,
    int nbP, int nbN)
{
  __shared__ int s[256];
  int b = blockIdx.x, t = threadIdx.x;
  const int* deg; const int* bsum; int* off; int* cur; int n; int nb;
  if (b < nbP) { deg = degP; bsum = bsumP; off = offP; cur = curP; n = nP; nb = nbP; }
  else { deg = degN; bsum = bsumN; off = offN; cur = curN; n = nN; nb = nbN; b -= nbP; }
  int base = b * 1024 + t * 4;
  int v0 = 0, v1 = 0, v2 = 0, v3 = 0;
  if (base + 0 < n) v0 = deg[base + 0];
  if (base + 1 < n) v1 = deg[base + 1];
  if (base + 2 < n) v2 = deg[base + 2];
  if (base + 3 < n) v3 = deg[base + 3];
  s[t] = v0 + v1 + v2 + v3;
  __syncthreads();
  for (int d = 1; d < 256; d <<= 1) {
    int v = (t >= d) ? s[t - d] : 0;
    __syncthreads();
    s[t] += v;
    __syncthreads();
  }
  int run = bsum[b] + ((t == 0) ? 0 : s[t - 1]);
  if (base + 0 < n) { off[base + 0] = run; cur[base + 0] = run; run += v0; }
  if (base + 1 < n) { off[base + 1] = run; cur[base + 1] = run; run += v1; }
  if (base + 2 < n) { off[base + 2] = run; cur[base + 2] = run; run += v2; }
  if (base + 3 < n) { off[base + 3] = run; cur[base + 3] = run; run += v3; }
  if (b == 0 && t == 0) off[n] = bsum[nb];
}

// fill: node graph gets plain src index; pair graph gets packed record
// recP[pos] = (pu[s], pv[s], bits(iso[s]), s)
__global__ void csr_fill_both(const int* __restrict__ ei, int E1,
                              const int* __restrict__ te, int E2,
                              const int* __restrict__ pu, const int* __restrict__ pv,
                              const float* __restrict__ iso,
                              int* __restrict__ curN, int* __restrict__ eidxN,
                              int* __restrict__ curP, int4* __restrict__ recP)
{
  int e = blockIdx.x * 256 + threadIdx.x;
  if (e < E1) {
    int s = ei[e], d = ei[E1 + e];
    int pos = atomicAdd(&curN[d], 1);
    eidxN[pos] = s;
  } else if (e < E1 + E2) {
    int i = e - E1;
    int s = te[i], d = te[E2 + i];
    int pos = atomicAdd(&curP[d], 1);
    recP[pos] = make_int4(pu[s], pv[s], __float_as_int(iso[s]), s);
  }
}

// ---------------- fused gathers (bf16 in / bf16 out, fp32 accumulate) ----------------
// out[r] = relu(pre[r] + sum msg[eidx[j]]); unroll x2 for MLP
__global__ __launch_bounds__(256) void gather_add_relu_bf(
    const unsigned short* __restrict__ pre, const unsigned short* __restrict__ msg,
    const int* __restrict__ off, const int* __restrict__ eidx,
    unsigned short* __restrict__ out, int R)
{
  int r = blockIdx.x * 8 + (threadIdx.x >> 5);
  if (r >= R) return;
  int f = (threadIdx.x & 31) * 4;
  float4 acc = ldbf4(pre + (size_t)r * 128 + f);
  int j = off[r], e1 = off[r + 1];
  for (; j + 1 < e1; j += 2) {
    int s0 = eidx[j], s1 = eidx[j + 1];
    float4 m0 = ldbf4(msg + (size_t)s0 * 128 + f);
    float4 m1 = ldbf4(msg + (size_t)s1 * 128 + f);
    acc.x += m0.x + m1.x; acc.y += m0.y + m1.y;
    acc.z += m0.z + m1.z; acc.w += m0.w + m1.w;
  }
  if (j < e1) {
    int s0 = eidx[j];
    float4 m0 = ldbf4(msg + (size_t)s0 * 128 + f);
    acc.x += m0.x; acc.y += m0.y; acc.z += m0.z; acc.w += m0.w;
  }
  stbf4(out + (size_t)r * 128 + f,
        make_float4(fmaxf(acc.x, 0.f), fmaxf(acc.y, 0.f),
                    fmaxf(acc.z, 0.f), fmaxf(acc.w, 0.f)));
}

// gather using packed edge records; unroll x2
__global__ __launch_bounds__(256) void gather_add_relu_rec(
    const unsigned short* __restrict__ pre, const unsigned short* __restrict__ msg,
    const int* __restrict__ off, const int4* __restrict__ rec,
    unsigned short* __restrict__ out, int R)
{
  int r = blockIdx.x * 8 + (threadIdx.x >> 5);
  if (r >= R) return;
  int f = (threadIdx.x & 31) * 4;
  float4 acc = ldbf4(pre + (size_t)r * 128 + f);
  int j = off[r], e1 = off[r + 1];
  for (; j + 1 < e1; j += 2) {
    int4 r0 = rec[j], r1 = rec[j + 1];
    float4 m0 = ldbf4(msg + (size_t)r0.w * 128 + f);
    float4 m1 = ldbf4(msg + (size_t)r1.w * 128 + f);
    acc.x += m0.x + m1.x; acc.y += m0.y + m1.y;
    acc.z += m0.z + m1.z; acc.w += m0.w + m1.w;
  }
  if (j < e1) {
    int4 r0 = rec[j];
    float4 m0 = ldbf4(msg + (size_t)r0.w * 128 + f);
    acc.x += m0.x; acc.y += m0.y; acc.z += m0.z; acc.w += m0.w;
  }
  stbf4(out + (size_t)r * 128 + f,
        make_float4(fmaxf(acc.x, 0.f), fmaxf(acc.y, 0.f),
                    fmaxf(acc.z, 0.f), fmaxf(acc.w, 0.f)));
}

// 2-set layer 0, fully fused, packed edge records, unroll x2
__global__ __launch_bounds__(256) void gather_two0_bf(
    const unsigned short* __restrict__ HU1, const unsigned short* __restrict__ HV1,
    const unsigned short* __restrict__ HU2, const unsigned short* __restrict__ HV2,
    const float* __restrict__ iso,
    const float* __restrict__ w1iso, const float* __restrict__ w2iso,
    const int* __restrict__ pu, const int* __restrict__ pv,
    const int* __restrict__ off, const int4* __restrict__ rec,
    unsigned short* __restrict__ out, int P)
{
  int p = blockIdx.x * 8 + (threadIdx.x >> 5);
  if (p >= P) return;
  int f = (threadIdx.x & 31) * 4;
  float4 wi1 = ld4(w1iso + f);
  float4 wi2 = ld4(w2iso + f);
  int u0 = pu[p], v0 = pv[p];
  float is0 = iso[p];
  float4 a = ldbf4(HU1 + (size_t)u0 * 128 + f);
  float4 b = ldbf4(HV1 + (size_t)v0 * 128 + f);
  float4 acc;
  acc.x = a.x + b.x + is0 * wi1.x;
  acc.y = a.y + b.y + is0 * wi1.y;
  acc.z = a.z + b.z + is0 * wi1.z;
  acc.w = a.w + b.w + is0 * wi1.w;
  int j = off[p], e1 = off[p + 1];
  for (; j + 1 < e1; j += 2) {
    int4 r0 = rec[j], r1 = rec[j + 1];
    float4 mu0 = ldbf4(HU2 + (size_t)r0.x * 128 + f);
    float4 mv0 = ldbf4(HV2 + (size_t)r0.y * 128 + f);
    float4 mu1 = ldbf4(HU2 + (size_t)r1.x * 128 + f);
    float4 mv1 = ldbf4(HV2 + (size_t)r1.y * 128 + f);
    float i0 = __int_as_float(r0.z), i1 = __int_as_float(r1.z);
    acc.x += mu0.x + mv0.x + i0 * wi2.x + mu1.x + mv1.x + i1 * wi2.x;
    acc.y += mu0.y + mv0.y + i0 * wi2.y + mu1.y + mv1.y + i1 * wi2.y;
    acc.z += mu0.z + mv0.z + i0 * wi2.z + mu1.z + mv1.z + i1 * wi2.z;
    acc.w += mu0.w + mv0.w + i0 * wi2.w + mu1.w + mv1.w + i1 * wi2.w;
  }
  if (j < e1) {
    int4 r0 = rec[j];
    float4 mu0 = ldbf4(HU2 + (size_t)r0.x * 128 + f);
    float4 mv0 = ldbf4(HV2 + (size_t)r0.y * 128 + f);
    float i0 = __int_as_float(r0.z);
    acc.x += mu0.x + mv0.x + i0 * wi2.x;
    acc.y += mu0.y + mv0.y + i0 * wi2.y;
    acc.z += mu0.z + mv0.z + i0 * wi2.z;
    acc.w += mu0.w + mv0.w + i0 * wi2.w;
  }
  stbf4(out + (size_t)p * 128 + f,
        make_float4(fmaxf(acc.x, 0.f), fmaxf(acc.y, 0.f),
                    fmaxf(acc.z, 0.f), fmaxf(acc.w, 0.f)));
}

// contiguous segment sum (128 wide), bf16 input
__global__ void seg_sum_bf(const unsigned short* __restrict__ X, float* __restrict__ out,
                           int rows_per_seg, int rows_per_chunk)
{
  int g = blockIdx.x, part = blockIdx.y, f = threadIdx.x;
  int r0 = part * rows_per_chunk;
  int r1 = r0 + rows_per_chunk;
  if (r1 > rows_per_seg) r1 = rows_per_seg;
  float s = 0.f;
  for (int i = r0; i < r1; ++i)
    s += bf2f(X[((size_t)g * rows_per_seg + i) * 128 + f]);
  atomicAdd(&out[g * 128 + f], s);
}

__global__ void classifier(const float* __restrict__ ge1, const float* __restrict__ ge2,
                           const float* __restrict__ W0, const float* __restrict__ b0,
                           const float* __restrict__ W1, const float* __restrict__ b1,
                           float* __restrict__ out)
{
  __shared__ float comb[256];
  __shared__ float hc[128];
  int g = blockIdx.x, t = threadIdx.x;  // 128 threads
  comb[t]       = ge1[g * 128 + t];
  comb[t + 128] = ge2[g * 128 + t];
  __syncthreads();
  float s = b0[t];
  for (int k = 0; k < 256; ++k) s += comb[k] * W0[k * 128 + t];
  hc[t] = fmaxf(s, 0.f);
  __syncthreads();
  if (t < 10) {
    float s2 = b1[t];
    for (int k = 0; k < 128; ++k) s2 += hc[k] * W1[k * 10 + t];
    out[g * 10 + t] = s2;
  }
}

extern "C" void kernel_launch(void* const* d_in, const int* in_sizes, int n_in,
                              void* d_out, int out_size, void* d_ws, size_t ws_size,
                              hipStream_t stream)
{
  (void)n_in; (void)out_size; (void)ws_size;
  const float* x       = (const float*)d_in[0];
  const float* g1_W1_0 = (const float*)d_in[1];
  const float* g1_W2_0 = (const float*)d_in[2];
  const float* g1_W1_1 = (const float*)d_in[3];
  const float* g1_W2_1 = (const float*)d_in[4];
  const float* g1_W1_2 = (const float*)d_in[5];
  const float* g1_W2_2 = (const float*)d_in[6];
  const float* k_W1_0  = (const float*)d_in[7];   // [257,128]
  const float* k_W2_0  = (const float*)d_in[8];   // [257,128]
  const float* k_W1_1  = (const float*)d_in[9];   // [128,128]
  const float* k_W2_1  = (const float*)d_in[10];  // [128,128]
  const float* c_W0    = (const float*)d_in[11];
  const float* c_b0    = (const float*)d_in[12];
  const float* c_W1    = (const float*)d_in[13];
  const float* c_b1    = (const float*)d_in[14];
  const float* iso     = (const float*)d_in[15];  // [P]
  const int*   ei      = (const int*)d_in[16];    // [2,E1]
  const int*   pu      = (const int*)d_in[18];    // [P]
  const int*   pv      = (const int*)d_in[19];    // [P]
  const int*   te      = (const int*)d_in[20];    // [2,E2]

  const int N  = in_sizes[0] / 64;   // 4096
  const int E1 = in_sizes[16] / 2;
  const int P  = in_sizes[18];       // 129024
  const int E2 = in_sizes[20] / 2;
  const int B  = 64;
  const int ppg = P / B;             // 2016

  const size_t NH = (size_t)N * 128;
  const size_t PH = (size_t)P * 128;

  float* ge1 = (float*)d_ws;          // 8192
  float* ge2 = ge1 + 8192;            // 8192 (adjacent: single memset)
  unsigned short* xb   = (unsigned short*)(ge2 + 8192);  // N*64
  unsigned short* hb   = xb + (size_t)N * 64;  // NH
  unsigned short* preN = hb + NH;              // NH
  unsigned short* msgN = preN + NH;            // NH
  unsigned short* HU1  = msgN + NH;            // NH
  unsigned short* HV1  = HU1 + NH;             // NH
  unsigned short* HU2  = HV1 + NH;             // NH
  unsigned short* HV2  = HU2 + NH;             // NH
  unsigned short* H2   = HV2 + NH;             // PH
  unsigned short* PRE2 = H2 + PH;              // PH
  unsigned short* MSG2 = PRE2 + PH;            // PH
  unsigned short* Wf0  = MSG2 + PH;            // 16384 (K=64)
  unsigned short* Wf1  = Wf0 + 16384;          // 32768
  unsigned short* Wf2  = Wf1 + 32768;
  unsigned short* Wf3  = Wf2 + 32768;
  unsigned short* Wf4  = Wf3 + 32768;
  unsigned short* Wf5  = Wf4 + 32768;

  size_t ipOff = ((size_t)(Wf5 + 32768 - (unsigned short*)d_ws) * 2 + 15) & ~(size_t)15;
  int4* recP = (int4*)((char*)d_ws + ipOff);     // E2 records (16B aligned)
  int* degN  = (int*)(recP + E2);    // N   } adjacent:
  int* degP  = degN + N;             // P   } single memset
  int* offN  = degP + P;             // N+1
  int* curN  = offN + N + 1;         // N
  int* eidxN = curN + N;             // E1
  int* offP  = eidxN + E1;           // P+1
  int* curP  = offP + P + 1;         // P
  int* bsumN = curP + P;             // nbN+1
  int* bsumP = bsumN + 8;            // nbP+1

  const int gatherN = (N + 7) / 8;
  const int gatherP = (P + 7) / 8;
  const int nbN = (N + 1023) / 1024;   // 4
  const int nbP = (P + 1023) / 1024;   // 126

  // ---- dtype prep ----
  convert_f2b<<<(N * 64 / 4 + 255) / 256, 256, 0, stream>>>(x, xb, N * 64 / 4);
  SwzArgs sa;
  sa.wa[0] = g1_W1_0;           sa.wb[0] = g1_W2_0;           sa.dst[0] = Wf0; sa.kclog[0] = 1;
  sa.wa[1] = g1_W1_1;           sa.wb[1] = g1_W2_1;           sa.dst[1] = Wf1; sa.kclog[1] = 2;
  sa.wa[2] = g1_W1_2;           sa.wb[2] = g1_W2_2;           sa.dst[2] = Wf2; sa.kclog[2] = 2;
  sa.wa[3] = k_W1_0;            sa.wb[3] = k_W2_0;            sa.dst[3] = Wf3; sa.kclog[3] = 2;
  sa.wa[4] = k_W1_0 + 128*128;  sa.wb[4] = k_W2_0 + 128*128;  sa.dst[4] = Wf4; sa.kclog[4] = 2;
  sa.wa[5] = k_W1_1;            sa.wb[5] = k_W2_1;            sa.dst[5] = Wf5; sa.kclog[5] = 2;
  swizzle_weights<<<dim3(16, 6), 256, 0, stream>>>(sa);

  // ---- build CSRs (merged) ----
  hipMemsetAsync(degN, 0, (size_t)(N + P) * 4, stream);
  csr_count_both<<<(E1 + E2 + 255) / 256, 256, 0, stream>>>(ei + E1, E1, te + E2, E2,
                                                            degN, degP);
  scan_reduce_both<<<nbP + nbN, 256, 0, stream>>>(degP, P, degN, N, bsumP, bsumN, nbP);
  scan_partials_both<<<2, 1024, 0, stream>>>(bsumP, nbP, bsumN, nbN);
  scan_final_both<<<nbP + nbN, 256, 0, stream>>>(degP, bsumP, offP, curP, P,
                                                 degN, bsumN, offN, curN, N, nbP, nbN);
  csr_fill_both<<<(E1 + E2 + 255) / 256, 256, 0, stream>>>(ei, E1, te, E2, pu, pv, iso,
                                                           curN, eidxN, curP, recP);

  // ---- node stage: 3 MP layers ----
  gemm_dual_mfma<2><<<N / 64, 256, 0, stream>>>(xb, Wf0, preN, msgN);
  gather_add_relu_bf<<<gatherN, 256, 0, stream>>>(preN, msgN, offN, eidxN, hb, N);
  gemm_dual_mfma<4><<<N / 64, 256, 0, stream>>>(hb, Wf1, preN, msgN);
  gather_add_relu_bf<<<gatherN, 256, 0, stream>>>(preN, msgN, offN, eidxN, hb, N);
  gemm_dual_mfma<4><<<N / 64, 256, 0, stream>>>(hb, Wf2, preN, msgN);
  gather_add_relu_bf<<<gatherN, 256, 0, stream>>>(preN, msgN, offN, eidxN, hb, N);

  // graph_emb_1 + graph_emb_2 accumulators (adjacent -> one memset)
  hipMemsetAsync(ge1, 0, 2 * 8192 * 4, stream);
  seg_sum_bf<<<dim3(B, 1), 128, 0, stream>>>(hb, ge1, 64, 64);

  // ---- 2-set stage ----
  gemm_dual_mfma<4><<<N / 64, 256, 0, stream>>>(hb, Wf3, HU1, HU2);
  gemm_dual_mfma<4><<<N / 64, 256, 0, stream>>>(hb, Wf4, HV1, HV2);

  gather_two0_bf<<<gatherP, 256, 0, stream>>>(HU1, HV1, HU2, HV2, iso,
                                              k_W1_0 + 256 * 128, k_W2_0 + 256 * 128,
                                              pu, pv, offP, recP, H2, P);

  gemm_dual_mfma<4><<<P / 64, 256, 0, stream>>>(H2, Wf5, PRE2, MSG2);
  gather_add_relu_rec<<<gatherP, 256, 0, stream>>>(PRE2, MSG2, offP, recP, H2, P);

  // graph_emb_2
  seg_sum_bf<<<dim3(B, 16), 128, 0, stream>>>(H2, ge2, ppg, (ppg + 15) / 16);

  // classifier
  classifier<<<B, 128, 0, stream>>>(ge1, ge2, c_W0, c_b0, c_W1, c_b1, (float*)d_out);
}